// Round 1
// baseline (1001.120 us; speedup 1.0000x reference)
//
#include <hip/hip_runtime.h>
#include <hip/hip_bf16.h>

#define NN 100000   // nodes
#define NE 1600000  // edges
#define NG 1000     // graphs
// DIN = DMID = 128, DGLOB = 64, DOUT = 2 (hardcoded below)

static inline int cdiv(int a, int b) { return (a + b - 1) / b; }

// ---------------------------------------------------------------- degree init
__global__ void k_init_deg(float* __restrict__ degf) {
    int i = blockIdx.x * 256 + threadIdx.x;
    if (i < NN) degf[i] = 1.0f;  // self-loop contributes 1
}

// in-degree count over col (dst)
__global__ void k_count(const int* __restrict__ col, float* __restrict__ degf) {
    int e = blockIdx.x * 256 + threadIdx.x;
    if (e < NE) atomicAdd(&degf[col[e]], 1.0f);
}

__global__ void k_dinv(const float* __restrict__ degf, float* __restrict__ dinv) {
    int i = blockIdx.x * 256 + threadIdx.x;
    if (i < NN) dinv[i] = rsqrtf(degf[i]);  // deg >= 1 always (self-loop)
}

// ---------------------------------------------------------------- CSR offsets
// exclusive scan of in-degree (deg-1) over NN elements, single block.
__global__ __launch_bounds__(1024) void k_scan(const float* __restrict__ degf,
                                               int* __restrict__ off,
                                               int* __restrict__ cursor) {
    __shared__ int part[1024];
    int t = threadIdx.x;
    const int chunk = (NN + 1023) / 1024;  // 98
    int b0 = t * chunk;
    int b1 = min(b0 + chunk, NN);
    int s = 0;
    for (int i = b0; i < b1; i++) s += (int)degf[i] - 1;
    part[t] = s;
    __syncthreads();
    for (int d = 1; d < 1024; d <<= 1) {
        int v = (t >= d) ? part[t - d] : 0;
        __syncthreads();
        part[t] += v;
        __syncthreads();
    }
    int run = part[t] - s;  // exclusive prefix
    for (int i = b0; i < b1; i++) {
        off[i] = run;
        cursor[i] = run;
        run += (int)degf[i] - 1;
    }
    if (t == 1023) off[NN] = run;  // == NE
}

// scatter edges into dst-sorted CSR; store src index + precomputed norm weight
__global__ void k_fill(const int* __restrict__ row, const int* __restrict__ col,
                       const float* __restrict__ dinv, int* __restrict__ cursor,
                       int* __restrict__ csr_src, float* __restrict__ csr_w) {
    int e = blockIdx.x * 256 + threadIdx.x;
    if (e < NE) {
        int s = row[e], d = col[e];
        int p = atomicAdd(&cursor[d], 1);
        csr_src[p] = s;
        csr_w[p] = dinv[s] * dinv[d];
    }
}

// ---------------------------------------------------------------- dense GEMM
// H[N,128] = X[N,128] @ W[128,128], f32. 32-row tile, K split in two 64-passes.
__global__ __launch_bounds__(256) void k_gemm(const float* __restrict__ X,
                                              const float* __restrict__ W,
                                              float* __restrict__ H) {
    __shared__ __align__(16) float Ws[64 * 128];  // 32 KB: k-slab of W
    __shared__ __align__(16) float Xs[32 * 64];   // 8 KB: 32 rows x 64 k
    int t = threadIdx.x;
    int row0 = blockIdx.x * 32;
    int tc = t & 31;   // col group: cols 4*tc .. 4*tc+3
    int tr = t >> 5;   // row group: rows 4*tr .. 4*tr+3
    float acc[4][4] = {{0.f}};

    for (int kk = 0; kk < 128; kk += 64) {
        // stage W rows kk..kk+63 (linear, coalesced float4)
        const float4* Wg = (const float4*)(W + kk * 128);
        float4* Ws4 = (float4*)Ws;
        for (int i = t; i < 64 * 128 / 4; i += 256) Ws4[i] = Wg[i];
        // stage X tile: 32 rows x 64 contiguous k each
        for (int i = t; i < 32 * 64 / 4; i += 256) {
            int r = i >> 4;   // 16 float4 per row
            int j = i & 15;
            ((float4*)Xs)[i] = *(const float4*)(X + (size_t)(row0 + r) * 128 + kk + j * 4);
        }
        __syncthreads();
        const float* Xb = Xs + tr * 4 * 64;
#pragma unroll 8
        for (int k = 0; k < 64; k++) {
            float4 w = *(const float4*)(Ws + k * 128 + tc * 4);
            float x0 = Xb[k];
            float x1 = Xb[64 + k];
            float x2 = Xb[128 + k];
            float x3 = Xb[192 + k];
            acc[0][0] = fmaf(x0, w.x, acc[0][0]); acc[0][1] = fmaf(x0, w.y, acc[0][1]);
            acc[0][2] = fmaf(x0, w.z, acc[0][2]); acc[0][3] = fmaf(x0, w.w, acc[0][3]);
            acc[1][0] = fmaf(x1, w.x, acc[1][0]); acc[1][1] = fmaf(x1, w.y, acc[1][1]);
            acc[1][2] = fmaf(x1, w.z, acc[1][2]); acc[1][3] = fmaf(x1, w.w, acc[1][3]);
            acc[2][0] = fmaf(x2, w.x, acc[2][0]); acc[2][1] = fmaf(x2, w.y, acc[2][1]);
            acc[2][2] = fmaf(x2, w.z, acc[2][2]); acc[2][3] = fmaf(x2, w.w, acc[2][3]);
            acc[3][0] = fmaf(x3, w.x, acc[3][0]); acc[3][1] = fmaf(x3, w.y, acc[3][1]);
            acc[3][2] = fmaf(x3, w.z, acc[3][2]); acc[3][3] = fmaf(x3, w.w, acc[3][3]);
        }
        __syncthreads();
    }
    for (int r = 0; r < 4; r++) {
        size_t gr = row0 + tr * 4 + r;
        *(float4*)(H + gr * 128 + tc * 4) =
            make_float4(acc[r][0], acc[r][1], acc[r][2], acc[r][3]);
    }
}

// ---------------------------------------------------------------- aggregation
// out[i] = relu( dinv[i]^2 * H[i] + sum_{e in CSR[i]} w_e * H[src_e] + bias )
// one wave per node; lane owns 2 columns (float2).
__global__ __launch_bounds__(256) void k_agg(const float* __restrict__ H,
                                             const int* __restrict__ off,
                                             const int* __restrict__ csr_src,
                                             const float* __restrict__ csr_w,
                                             const float* __restrict__ dinv,
                                             const float* __restrict__ bias,
                                             float* __restrict__ out) {
    int node = blockIdx.x * 4 + (threadIdx.x >> 6);
    int lane = threadIdx.x & 63;
    int c = lane * 2;
    float di = dinv[node];
    float w0 = di * di;  // self-loop norm
    float2 h = *(const float2*)(H + (size_t)node * 128 + c);
    float ax = w0 * h.x, ay = w0 * h.y;
    int e0 = off[node], e1 = off[node + 1];
    for (int e = e0; e < e1; e++) {
        int s = csr_src[e];
        float w = csr_w[e];
        float2 hs = *(const float2*)(H + (size_t)s * 128 + c);
        ax = fmaf(w, hs.x, ax);
        ay = fmaf(w, hs.y, ay);
    }
    float2 b = *(const float2*)(bias + c);
    ax = fmaxf(ax + b.x, 0.f);
    ay = fmaxf(ay + b.y, 0.f);
    *(float2*)(out + (size_t)node * 128 + c) = make_float2(ax, ay);
}

// ---------------------------------------------------------------- mean pool
// batch[] is sorted; each block binary-searches its graph's node range.
__global__ __launch_bounds__(128) void k_pool(const float* __restrict__ A,
                                              const int* __restrict__ batch,
                                              float* __restrict__ emb) {
    int g = blockIdx.x;
    int c = threadIdx.x;  // 128 columns
    int lo = 0, hi = NN;
    while (lo < hi) { int m = (lo + hi) >> 1; if (batch[m] < g) lo = m + 1; else hi = m; }
    int start = lo;
    hi = NN;
    while (lo < hi) { int m = (lo + hi) >> 1; if (batch[m] < g + 1) lo = m + 1; else hi = m; }
    int end = lo;
    float s = 0.f;
    for (int i = start; i < end; i++) s += A[(size_t)i * 128 + c];
    int cnt = end - start;
    emb[g * 128 + c] = s / (float)max(cnt, 1);
}

// ---------------------------------------------------------------- head MLP
// out[g] = relu([emb[g], u[g]] @ Wh1 + bh1) @ Wh2 + bh2
__global__ __launch_bounds__(128) void k_head(const float* __restrict__ emb,
                                              const float* __restrict__ u,
                                              const float* __restrict__ Wh1,
                                              const float* __restrict__ bh1,
                                              const float* __restrict__ Wh2,
                                              const float* __restrict__ bh2,
                                              float* __restrict__ out) {
    __shared__ float hc[192];
    __shared__ float tt[128];
    int g = blockIdx.x, t = threadIdx.x;
    hc[t] = emb[g * 128 + t];
    if (t < 64) hc[128 + t] = u[g * 64 + t];
    __syncthreads();
    float acc = bh1[t];
    for (int k = 0; k < 192; k++) acc = fmaf(hc[k], Wh1[k * 128 + t], acc);
    tt[t] = fmaxf(acc, 0.f);
    __syncthreads();
    if (t < 2) {
        float o = bh2[t];
        for (int c2 = 0; c2 < 128; c2++) o = fmaf(tt[c2], Wh2[c2 * 2 + t], o);
        out[g * 2 + t] = o;
    }
}

// ---------------------------------------------------------------- launcher
extern "C" void kernel_launch(void* const* d_in, const int* in_sizes, int n_in,
                              void* d_out, int out_size, void* d_ws, size_t ws_size,
                              hipStream_t stream) {
    const float* x   = (const float*)d_in[0];
    const int*   ei  = (const int*)d_in[1];
    const int*   row = ei;        // edge_index[0] = src
    const int*   col = ei + NE;   // edge_index[1] = dst
    const float* u   = (const float*)d_in[2];
    const int*   batch = (const int*)d_in[3];
    // d_in[4] = batch_size scalar (== NG), hardcoded
    const float* W1  = (const float*)d_in[5];
    const float* b1  = (const float*)d_in[6];
    const float* W2  = (const float*)d_in[7];
    const float* b2  = (const float*)d_in[8];
    const float* Wh1 = (const float*)d_in[9];
    const float* bh1 = (const float*)d_in[10];
    const float* Wh2 = (const float*)d_in[11];
    const float* bh2 = (const float*)d_in[12];
    float* out = (float*)d_out;

    char* ws = (char*)d_ws;
    size_t o = 0;
    auto alloc = [&](size_t bytes) -> void* {
        void* p = ws + o;
        o += (bytes + 511) & ~(size_t)511;
        return p;
    };
    float* Hbuf    = (float*)alloc((size_t)NN * 128 * 4);  // GEMM output
    float* Abuf    = (float*)alloc((size_t)NN * 128 * 4);  // aggregation output
    float* degf    = (float*)alloc((size_t)NN * 4);
    float* dinv    = (float*)alloc((size_t)NN * 4);
    int*   off     = (int*)alloc((size_t)(NN + 1) * 4);
    int*   cursor  = (int*)alloc((size_t)NN * 4);
    int*   csr_src = (int*)alloc((size_t)NE * 4);
    float* csr_w   = (float*)alloc((size_t)NE * 4);
    float* emb     = (float*)alloc((size_t)NG * 128 * 4);

    // --- normalization + CSR build ---
    k_init_deg<<<cdiv(NN, 256), 256, 0, stream>>>(degf);
    k_count<<<cdiv(NE, 256), 256, 0, stream>>>(col, degf);
    k_dinv<<<cdiv(NN, 256), 256, 0, stream>>>(degf, dinv);
    k_scan<<<1, 1024, 0, stream>>>(degf, off, cursor);
    k_fill<<<cdiv(NE, 256), 256, 0, stream>>>(row, col, dinv, cursor, csr_src, csr_w);

    // --- layer 1: H = x @ W1 ; A = relu(aggregate(H) + b1) ---
    k_gemm<<<NN / 32, 256, 0, stream>>>(x, W1, Hbuf);
    k_agg<<<NN / 4, 256, 0, stream>>>(Hbuf, off, csr_src, csr_w, dinv, b1, Abuf);

    // --- layer 2 ---
    k_gemm<<<NN / 32, 256, 0, stream>>>(Abuf, W2, Hbuf);
    k_agg<<<NN / 4, 256, 0, stream>>>(Hbuf, off, csr_src, csr_w, dinv, b2, Abuf);

    // --- mean pool + head ---
    k_pool<<<NG, 128, 0, stream>>>(Abuf, batch, emb);
    k_head<<<NG, 128, 0, stream>>>(emb, u, Wh1, bh1, Wh2, bh2, out);
}

// Round 2
// 755.779 us; speedup vs baseline: 1.3246x; 1.3246x over previous
//
#include <hip/hip_runtime.h>
#include <hip/hip_bf16.h>

#define NN 100000   // nodes
#define NE 1600000  // edges
#define NG 1000     // graphs
#define NPAD (98 * 1024)  // NN rounded up to 98 scan blocks of 1024
// DIN = DMID = 128, DGLOB = 64, DOUT = 2 (hardcoded below)

static inline int cdiv(int a, int b) { return (a + b - 1) / b; }

// ---------------------------------------------------------------- degree
__global__ void k_init_deg(int* __restrict__ deg) {
    int i = blockIdx.x * 256 + threadIdx.x;
    if (i < NPAD) deg[i] = 0;  // raw in-degree (self-loop added later)
}

__global__ void k_count(const int* __restrict__ col, int* __restrict__ deg) {
    int e = blockIdx.x * 256 + threadIdx.x;
    if (e < NE) atomicAdd(&deg[col[e]], 1);
}

__global__ void k_dinv(const int* __restrict__ deg, float* __restrict__ dinv) {
    int i = blockIdx.x * 256 + threadIdx.x;
    if (i < NN) dinv[i] = rsqrtf((float)(deg[i] + 1));  // +1 self-loop
}

// ------------------------------------------------- hierarchical CSR scan
// pass 1: per-block (1024 elements) sums
__global__ __launch_bounds__(256) void k_scan1(const int* __restrict__ deg,
                                               int* __restrict__ bsum) {
    int t = threadIdx.x;
    int4 v = *(const int4*)(deg + blockIdx.x * 1024 + t * 4);
    int s = v.x + v.y + v.z + v.w;
    for (int d = 32; d; d >>= 1) s += __shfl_down(s, d);  // wave64 reduce
    __shared__ int ws[4];
    if ((t & 63) == 0) ws[t >> 6] = s;
    __syncthreads();
    if (t == 0) bsum[blockIdx.x] = ws[0] + ws[1] + ws[2] + ws[3];
}

// pass 2: exclusive scan of the 98 block sums (single tiny block)
__global__ __launch_bounds__(128) void k_scan2(const int* __restrict__ bsum,
                                               int* __restrict__ boff,
                                               int* __restrict__ off) {
    int t = threadIdx.x;
    int v = (t < 98) ? bsum[t] : 0;
    __shared__ int sh[128];
    sh[t] = v;
    __syncthreads();
    for (int d = 1; d < 128; d <<= 1) {
        int u = (t >= d) ? sh[t - d] : 0;
        __syncthreads();
        sh[t] += u;
        __syncthreads();
    }
    if (t < 98) boff[t] = sh[t] - v;  // exclusive prefix
    if (t == 0) off[NN] = NE;         // total = sum of in-degrees
}

// pass 3: local prefix + block offset -> off[] and cursor[]
__global__ __launch_bounds__(256) void k_scan3(const int* __restrict__ deg,
                                               const int* __restrict__ boff,
                                               int* __restrict__ off,
                                               int* __restrict__ cursor) {
    int t = threadIdx.x;
    int base = blockIdx.x * 1024 + t * 4;
    int4 v = *(const int4*)(deg + base);
    int tsum = v.x + v.y + v.z + v.w;
    __shared__ int sh[256];
    sh[t] = tsum;
    __syncthreads();
    for (int d = 1; d < 256; d <<= 1) {
        int u = (t >= d) ? sh[t - d] : 0;
        __syncthreads();
        sh[t] += u;
        __syncthreads();
    }
    int run = boff[blockIdx.x] + sh[t] - tsum;
    int o1 = run + v.x, o2 = o1 + v.y, o3 = o2 + v.z;
    if (base < NN)     { off[base]     = run; cursor[base]     = run; }
    if (base + 1 < NN) { off[base + 1] = o1;  cursor[base + 1] = o1;  }
    if (base + 2 < NN) { off[base + 2] = o2;  cursor[base + 2] = o2;  }
    if (base + 3 < NN) { off[base + 3] = o3;  cursor[base + 3] = o3;  }
}

// scatter edges into dst-sorted CSR; store src index + precomputed norm weight
__global__ void k_fill(const int* __restrict__ row, const int* __restrict__ col,
                       const float* __restrict__ dinv, int* __restrict__ cursor,
                       int* __restrict__ csr_src, float* __restrict__ csr_w) {
    int e = blockIdx.x * 256 + threadIdx.x;
    if (e < NE) {
        int s = row[e], d = col[e];
        int p = atomicAdd(&cursor[d], 1);
        csr_src[p] = s;
        csr_w[p] = dinv[s] * dinv[d];
    }
}

// ---------------------------------------------------------------- dense GEMM
// H[N,128] = X[N,128] @ W[128,128], f32. 32-row tile, K split in two 64-passes.
__global__ __launch_bounds__(256) void k_gemm(const float* __restrict__ X,
                                              const float* __restrict__ W,
                                              float* __restrict__ H) {
    __shared__ __align__(16) float Ws[64 * 128];  // 32 KB: k-slab of W
    __shared__ __align__(16) float Xs[32 * 64];   // 8 KB: 32 rows x 64 k
    int t = threadIdx.x;
    int row0 = blockIdx.x * 32;
    int tc = t & 31;   // col group: cols 4*tc .. 4*tc+3
    int tr = t >> 5;   // row group: rows 4*tr .. 4*tr+3
    float acc[4][4] = {{0.f}};

    for (int kk = 0; kk < 128; kk += 64) {
        const float4* Wg = (const float4*)(W + kk * 128);
        float4* Ws4 = (float4*)Ws;
        for (int i = t; i < 64 * 128 / 4; i += 256) Ws4[i] = Wg[i];
        for (int i = t; i < 32 * 64 / 4; i += 256) {
            int r = i >> 4;
            int j = i & 15;
            ((float4*)Xs)[i] = *(const float4*)(X + (size_t)(row0 + r) * 128 + kk + j * 4);
        }
        __syncthreads();
        const float* Xb = Xs + tr * 4 * 64;
#pragma unroll 8
        for (int k = 0; k < 64; k++) {
            float4 w = *(const float4*)(Ws + k * 128 + tc * 4);
            float x0 = Xb[k];
            float x1 = Xb[64 + k];
            float x2 = Xb[128 + k];
            float x3 = Xb[192 + k];
            acc[0][0] = fmaf(x0, w.x, acc[0][0]); acc[0][1] = fmaf(x0, w.y, acc[0][1]);
            acc[0][2] = fmaf(x0, w.z, acc[0][2]); acc[0][3] = fmaf(x0, w.w, acc[0][3]);
            acc[1][0] = fmaf(x1, w.x, acc[1][0]); acc[1][1] = fmaf(x1, w.y, acc[1][1]);
            acc[1][2] = fmaf(x1, w.z, acc[1][2]); acc[1][3] = fmaf(x1, w.w, acc[1][3]);
            acc[2][0] = fmaf(x2, w.x, acc[2][0]); acc[2][1] = fmaf(x2, w.y, acc[2][1]);
            acc[2][2] = fmaf(x2, w.z, acc[2][2]); acc[2][3] = fmaf(x2, w.w, acc[2][3]);
            acc[3][0] = fmaf(x3, w.x, acc[3][0]); acc[3][1] = fmaf(x3, w.y, acc[3][1]);
            acc[3][2] = fmaf(x3, w.z, acc[3][2]); acc[3][3] = fmaf(x3, w.w, acc[3][3]);
        }
        __syncthreads();
    }
    for (int r = 0; r < 4; r++) {
        size_t gr = row0 + tr * 4 + r;
        *(float4*)(H + gr * 128 + tc * 4) =
            make_float4(acc[r][0], acc[r][1], acc[r][2], acc[r][3]);
    }
}

// ---------------------------------------------------------------- aggregation
// out[i] = relu( dinv[i]^2 * H[i] + sum_{e in CSR[i]} w_e * H[src_e] + bias )
// one wave per node; lane owns 2 columns (float2).
__global__ __launch_bounds__(256) void k_agg(const float* __restrict__ H,
                                             const int* __restrict__ off,
                                             const int* __restrict__ csr_src,
                                             const float* __restrict__ csr_w,
                                             const float* __restrict__ dinv,
                                             const float* __restrict__ bias,
                                             float* __restrict__ out) {
    int node = blockIdx.x * 4 + (threadIdx.x >> 6);
    int lane = threadIdx.x & 63;
    int c = lane * 2;
    float di = dinv[node];
    float w0 = di * di;  // self-loop norm
    float2 h = *(const float2*)(H + (size_t)node * 128 + c);
    float ax = w0 * h.x, ay = w0 * h.y;
    int e0 = off[node], e1 = off[node + 1];
    for (int e = e0; e < e1; e++) {
        int s = csr_src[e];
        float w = csr_w[e];
        float2 hs = *(const float2*)(H + (size_t)s * 128 + c);
        ax = fmaf(w, hs.x, ax);
        ay = fmaf(w, hs.y, ay);
    }
    float2 b = *(const float2*)(bias + c);
    ax = fmaxf(ax + b.x, 0.f);
    ay = fmaxf(ay + b.y, 0.f);
    *(float2*)(out + (size_t)node * 128 + c) = make_float2(ax, ay);
}

// ---------------------------------------------------------------- mean pool
__global__ __launch_bounds__(128) void k_pool(const float* __restrict__ A,
                                              const int* __restrict__ batch,
                                              float* __restrict__ emb) {
    int g = blockIdx.x;
    int c = threadIdx.x;  // 128 columns
    int lo = 0, hi = NN;
    while (lo < hi) { int m = (lo + hi) >> 1; if (batch[m] < g) lo = m + 1; else hi = m; }
    int start = lo;
    hi = NN;
    while (lo < hi) { int m = (lo + hi) >> 1; if (batch[m] < g + 1) lo = m + 1; else hi = m; }
    int end = lo;
    float s = 0.f;
    for (int i = start; i < end; i++) s += A[(size_t)i * 128 + c];
    int cnt = end - start;
    emb[g * 128 + c] = s / (float)max(cnt, 1);
}

// ---------------------------------------------------------------- head MLP
__global__ __launch_bounds__(128) void k_head(const float* __restrict__ emb,
                                              const float* __restrict__ u,
                                              const float* __restrict__ Wh1,
                                              const float* __restrict__ bh1,
                                              const float* __restrict__ Wh2,
                                              const float* __restrict__ bh2,
                                              float* __restrict__ out) {
    __shared__ float hc[192];
    __shared__ float tt[128];
    int g = blockIdx.x, t = threadIdx.x;
    hc[t] = emb[g * 128 + t];
    if (t < 64) hc[128 + t] = u[g * 64 + t];
    __syncthreads();
    float acc = bh1[t];
    for (int k = 0; k < 192; k++) acc = fmaf(hc[k], Wh1[k * 128 + t], acc);
    tt[t] = fmaxf(acc, 0.f);
    __syncthreads();
    if (t < 2) {
        float o = bh2[t];
        for (int c2 = 0; c2 < 128; c2++) o = fmaf(tt[c2], Wh2[c2 * 2 + t], o);
        out[g * 2 + t] = o;
    }
}

// ---------------------------------------------------------------- launcher
extern "C" void kernel_launch(void* const* d_in, const int* in_sizes, int n_in,
                              void* d_out, int out_size, void* d_ws, size_t ws_size,
                              hipStream_t stream) {
    const float* x   = (const float*)d_in[0];
    const int*   ei  = (const int*)d_in[1];
    const int*   row = ei;        // edge_index[0] = src
    const int*   col = ei + NE;   // edge_index[1] = dst
    const float* u   = (const float*)d_in[2];
    const int*   batch = (const int*)d_in[3];
    // d_in[4] = batch_size scalar (== NG), hardcoded
    const float* W1  = (const float*)d_in[5];
    const float* b1  = (const float*)d_in[6];
    const float* W2  = (const float*)d_in[7];
    const float* b2  = (const float*)d_in[8];
    const float* Wh1 = (const float*)d_in[9];
    const float* bh1 = (const float*)d_in[10];
    const float* Wh2 = (const float*)d_in[11];
    const float* bh2 = (const float*)d_in[12];
    float* out = (float*)d_out;

    char* ws = (char*)d_ws;
    size_t o = 0;
    auto alloc = [&](size_t bytes) -> void* {
        void* p = ws + o;
        o += (bytes + 511) & ~(size_t)511;
        return p;
    };
    float* Hbuf    = (float*)alloc((size_t)NN * 128 * 4);  // GEMM output
    float* Abuf    = (float*)alloc((size_t)NN * 128 * 4);  // aggregation output
    int*   deg     = (int*)alloc((size_t)NPAD * 4);
    float* dinv    = (float*)alloc((size_t)NN * 4);
    int*   off     = (int*)alloc((size_t)(NN + 1) * 4);
    int*   cursor  = (int*)alloc((size_t)NN * 4);
    int*   bsum    = (int*)alloc((size_t)128 * 4);
    int*   boff    = (int*)alloc((size_t)128 * 4);
    int*   csr_src = (int*)alloc((size_t)NE * 4);
    float* csr_w   = (float*)alloc((size_t)NE * 4);
    float* emb     = (float*)alloc((size_t)NG * 128 * 4);

    // --- normalization + CSR build ---
    k_init_deg<<<cdiv(NPAD, 256), 256, 0, stream>>>(deg);
    k_count<<<cdiv(NE, 256), 256, 0, stream>>>(col, deg);
    k_dinv<<<cdiv(NN, 256), 256, 0, stream>>>(deg, dinv);
    k_scan1<<<98, 256, 0, stream>>>(deg, bsum);
    k_scan2<<<1, 128, 0, stream>>>(bsum, boff, off);
    k_scan3<<<98, 256, 0, stream>>>(deg, boff, off, cursor);
    k_fill<<<cdiv(NE, 256), 256, 0, stream>>>(row, col, dinv, cursor, csr_src, csr_w);

    // --- layer 1: H = x @ W1 ; A = relu(aggregate(H) + b1) ---
    k_gemm<<<NN / 32, 256, 0, stream>>>(x, W1, Hbuf);
    k_agg<<<NN / 4, 256, 0, stream>>>(Hbuf, off, csr_src, csr_w, dinv, b1, Abuf);

    // --- layer 2 ---
    k_gemm<<<NN / 32, 256, 0, stream>>>(Abuf, W2, Hbuf);
    k_agg<<<NN / 4, 256, 0, stream>>>(Hbuf, off, csr_src, csr_w, dinv, b2, Abuf);

    // --- mean pool + head ---
    k_pool<<<NG, 128, 0, stream>>>(Abuf, batch, emb);
    k_head<<<NG, 128, 0, stream>>>(emb, u, Wh1, bh1, Wh2, bh2, out);
}

// Round 3
// 713.721 us; speedup vs baseline: 1.4027x; 1.0589x over previous
//
#include <hip/hip_runtime.h>
#include <hip/hip_bf16.h>

#define NN 100000   // nodes
#define NE 1600000  // edges
#define NG 1000     // graphs
#define NPAD (98 * 1024)  // NN rounded up to 98 scan blocks of 1024

typedef short short8 __attribute__((ext_vector_type(8)));
typedef float f32x4 __attribute__((ext_vector_type(4)));

static inline int cdiv(int a, int b) { return (a + b - 1) / b; }

// f32 -> bf16 (RNE) and helpers
__device__ __forceinline__ unsigned short f2b(float f) {
    unsigned int u = __float_as_uint(f);
    u += 0x7fff + ((u >> 16) & 1);
    return (unsigned short)(u >> 16);
}
__device__ __forceinline__ unsigned int pack2(float lo, float hi) {
    return (unsigned int)f2b(lo) | ((unsigned int)f2b(hi) << 16);
}
__device__ __forceinline__ float bf_lo(unsigned int v) { return __uint_as_float(v << 16); }
__device__ __forceinline__ float bf_hi(unsigned int v) { return __uint_as_float(v & 0xffff0000u); }

// ---------------------------------------------------------------- degree
__global__ void k_init_deg(int* __restrict__ deg) {
    int i = blockIdx.x * 256 + threadIdx.x;
    if (i < NPAD) deg[i] = 0;
}

__global__ void k_count(const int* __restrict__ col, int* __restrict__ deg) {
    int e = blockIdx.x * 256 + threadIdx.x;
    if (e < NE) atomicAdd(&deg[col[e]], 1);
}

__global__ void k_dinv(const int* __restrict__ deg, float* __restrict__ dinv) {
    int i = blockIdx.x * 256 + threadIdx.x;
    if (i < NN) dinv[i] = rsqrtf((float)(deg[i] + 1));  // +1 self-loop
}

// ------------------------------------------------- hierarchical CSR scan
__global__ __launch_bounds__(256) void k_scan1(const int* __restrict__ deg,
                                               int* __restrict__ bsum) {
    int t = threadIdx.x;
    int4 v = *(const int4*)(deg + blockIdx.x * 1024 + t * 4);
    int s = v.x + v.y + v.z + v.w;
    for (int d = 32; d; d >>= 1) s += __shfl_down(s, d);
    __shared__ int ws[4];
    if ((t & 63) == 0) ws[t >> 6] = s;
    __syncthreads();
    if (t == 0) bsum[blockIdx.x] = ws[0] + ws[1] + ws[2] + ws[3];
}

__global__ __launch_bounds__(128) void k_scan2(const int* __restrict__ bsum,
                                               int* __restrict__ boff,
                                               int* __restrict__ off) {
    int t = threadIdx.x;
    int v = (t < 98) ? bsum[t] : 0;
    __shared__ int sh[128];
    sh[t] = v;
    __syncthreads();
    for (int d = 1; d < 128; d <<= 1) {
        int u = (t >= d) ? sh[t - d] : 0;
        __syncthreads();
        sh[t] += u;
        __syncthreads();
    }
    if (t < 98) boff[t] = sh[t] - v;
    if (t == 0) off[NN] = NE;
}

__global__ __launch_bounds__(256) void k_scan3(const int* __restrict__ deg,
                                               const int* __restrict__ boff,
                                               int* __restrict__ off,
                                               int* __restrict__ cursor) {
    int t = threadIdx.x;
    int base = blockIdx.x * 1024 + t * 4;
    int4 v = *(const int4*)(deg + base);
    int tsum = v.x + v.y + v.z + v.w;
    __shared__ int sh[256];
    sh[t] = tsum;
    __syncthreads();
    for (int d = 1; d < 256; d <<= 1) {
        int u = (t >= d) ? sh[t - d] : 0;
        __syncthreads();
        sh[t] += u;
        __syncthreads();
    }
    int run = boff[blockIdx.x] + sh[t] - tsum;
    int o1 = run + v.x, o2 = o1 + v.y, o3 = o2 + v.z;
    if (base < NN)     { off[base]     = run; cursor[base]     = run; }
    if (base + 1 < NN) { off[base + 1] = o1;  cursor[base + 1] = o1;  }
    if (base + 2 < NN) { off[base + 2] = o2;  cursor[base + 2] = o2;  }
    if (base + 3 < NN) { off[base + 3] = o3;  cursor[base + 3] = o3;  }
}

// scatter edges into dst-sorted CSR (src only; norms folded into features)
__global__ void k_fill(const int* __restrict__ row, const int* __restrict__ col,
                       int* __restrict__ cursor, int* __restrict__ csr_src) {
    int e = blockIdx.x * 256 + threadIdx.x;
    if (e < NE) {
        int s = row[e], d = col[e];
        int p = atomicAdd(&cursor[d], 1);
        csr_src[p] = s;
    }
}

// ---------------------------------------------------------------- cast x->bf16
__global__ void k_cast(const float* __restrict__ X, uint* __restrict__ O) {
    int i = blockIdx.x * 256 + threadIdx.x;  // 8 floats each
    const float4* X4 = (const float4*)X;
    float4 v0 = X4[i * 2], v1 = X4[i * 2 + 1];
    uint4 o;
    o.x = pack2(v0.x, v0.y); o.y = pack2(v0.z, v0.w);
    o.z = pack2(v1.x, v1.y); o.w = pack2(v1.z, v1.w);
    ((uint4*)O)[i] = o;
}

// ---------------------------------------------------------------- MFMA GEMM
// Hs[r][c] = dinv[r] * sum_k A[r][k] * W[k][c]   (A bf16, W f32, Hs bf16)
// block = 256 thr (4 waves), 128 rows x 128 cols per block.
// W transposed into LDS as bf16 with XOR-16B-chunk swizzle (conflict-free b128).
__global__ __launch_bounds__(256) void k_gemm(const unsigned short* __restrict__ A,
                                              const float* __restrict__ W,
                                              const float* __restrict__ dinv,
                                              unsigned short* __restrict__ Hs) {
    __shared__ __align__(16) unsigned short Wt[128 * 128];  // 32 KB
    int t = threadIdx.x;
    // stage: W (f32 row-major) -> Wt[n][k] bf16, swizzled at 16B-chunk granularity
    {
        const float4* W4 = (const float4*)W;  // 4096 float4
#pragma unroll
        for (int ii = 0; ii < 16; ii++) {
            int idx = t + ii * 256;
            float4 v = W4[idx];
            int k = idx >> 5;         // W row (k index)
            int n0 = (idx & 31) * 4;  // W col (n index)
            float vv[4] = {v.x, v.y, v.z, v.w};
#pragma unroll
            for (int j = 0; j < 4; j++) {
                int n = n0 + j;
                int byte = n * 256 + ((((k >> 3) ^ (n & 15))) << 4) + ((k & 7) << 1);
                *(unsigned short*)((char*)Wt + byte) = f2b(vv[j]);
            }
        }
    }
    __syncthreads();

    int lane = t & 63, wid = t >> 6;
    int n16 = lane & 15, quad = lane >> 4;  // 0..3
    int row_base = blockIdx.x * 128 + wid * 32;

    // preload A fragments: a[rt][ks] = A[row][ks*32 + quad*8 .. +7]
    short8 a[2][4];
#pragma unroll
    for (int rt = 0; rt < 2; rt++) {
        int r = row_base + rt * 16 + n16;
        if (r > NN - 1) r = NN - 1;
        const unsigned short* ap = A + (size_t)r * 128 + quad * 8;
#pragma unroll
        for (int ks = 0; ks < 4; ks++)
            a[rt][ks] = *(const short8*)(ap + ks * 32);
    }

    f32x4 acc[2][8];
#pragma unroll
    for (int rt = 0; rt < 2; rt++)
#pragma unroll
        for (int ct = 0; ct < 8; ct++)
            acc[rt][ct] = (f32x4){0.f, 0.f, 0.f, 0.f};

#pragma unroll
    for (int ks = 0; ks < 4; ks++) {
#pragma unroll
        for (int ct = 0; ct < 8; ct++) {
            short8 b = *(const short8*)((const char*)Wt +
                        (ct * 16 + n16) * 256 + ((((ks << 2) + quad) ^ n16) << 4));
            acc[0][ct] = __builtin_amdgcn_mfma_f32_16x16x32_bf16(a[0][ks], b, acc[0][ct], 0, 0, 0);
            acc[1][ct] = __builtin_amdgcn_mfma_f32_16x16x32_bf16(a[1][ks], b, acc[1][ct], 0, 0, 0);
        }
    }

    // epilogue: D[row=quad*4+reg][col=ct*16+n16]; scale by dinv, store bf16
#pragma unroll
    for (int rt = 0; rt < 2; rt++) {
#pragma unroll
        for (int reg = 0; reg < 4; reg++) {
            int row = row_base + rt * 16 + quad * 4 + reg;
            if (row < NN) {
                float di = dinv[row];
                unsigned short* hp = Hs + (size_t)row * 128 + n16;
#pragma unroll
                for (int ct = 0; ct < 8; ct++)
                    hp[ct * 16] = f2b(acc[rt][ct][reg] * di);
            }
        }
    }
}

// ---------------------------------------------------------------- aggregation
// out[i] = relu( dinv[i] * (Hs[i] + sum_e Hs[src_e]) + bias )
// one wave per node; lane owns 2 bf16 columns (one uint).
template <bool OBF>
__global__ __launch_bounds__(256) void k_agg(const unsigned int* __restrict__ Hu,
                                             const int* __restrict__ off,
                                             const int* __restrict__ csr_src,
                                             const float* __restrict__ dinv,
                                             const float* __restrict__ bias,
                                             void* __restrict__ outp) {
    int node = blockIdx.x * 4 + (threadIdx.x >> 6);
    int lane = threadIdx.x & 63;
    unsigned int v = Hu[(size_t)node * 64 + lane];  // self term (already dinv-scaled)
    float ax = bf_lo(v), ay = bf_hi(v);
    int e0 = off[node], e1 = off[node + 1];
    for (int e = e0; e < e1; e++) {
        int s = csr_src[e];
        unsigned int w = Hu[(size_t)s * 64 + lane];
        ax += bf_lo(w);
        ay += bf_hi(w);
    }
    float di = dinv[node];
    float2 b = *(const float2*)(bias + lane * 2);
    ax = fmaxf(fmaf(di, ax, b.x), 0.f);
    ay = fmaxf(fmaf(di, ay, b.y), 0.f);
    if (OBF) {
        ((unsigned int*)outp)[(size_t)node * 64 + lane] = pack2(ax, ay);
    } else {
        ((float2*)outp)[(size_t)node * 64 + lane] = make_float2(ax, ay);
    }
}

// ---------------------------------------------------------------- mean pool
__global__ __launch_bounds__(128) void k_pool(const float* __restrict__ A,
                                              const int* __restrict__ batch,
                                              float* __restrict__ emb) {
    int g = blockIdx.x;
    int c = threadIdx.x;
    int lo = 0, hi = NN;
    while (lo < hi) { int m = (lo + hi) >> 1; if (batch[m] < g) lo = m + 1; else hi = m; }
    int start = lo;
    hi = NN;
    while (lo < hi) { int m = (lo + hi) >> 1; if (batch[m] < g + 1) lo = m + 1; else hi = m; }
    int end = lo;
    float s = 0.f;
    for (int i = start; i < end; i++) s += A[(size_t)i * 128 + c];
    int cnt = end - start;
    emb[g * 128 + c] = s / (float)max(cnt, 1);
}

// ---------------------------------------------------------------- head MLP
__global__ __launch_bounds__(128) void k_head(const float* __restrict__ emb,
                                              const float* __restrict__ u,
                                              const float* __restrict__ Wh1,
                                              const float* __restrict__ bh1,
                                              const float* __restrict__ Wh2,
                                              const float* __restrict__ bh2,
                                              float* __restrict__ out) {
    __shared__ float hc[192];
    __shared__ float tt[128];
    int g = blockIdx.x, t = threadIdx.x;
    hc[t] = emb[g * 128 + t];
    if (t < 64) hc[128 + t] = u[g * 64 + t];
    __syncthreads();
    float acc = bh1[t];
    for (int k = 0; k < 192; k++) acc = fmaf(hc[k], Wh1[k * 128 + t], acc);
    tt[t] = fmaxf(acc, 0.f);
    __syncthreads();
    if (t < 2) {
        float o = bh2[t];
        for (int c2 = 0; c2 < 128; c2++) o = fmaf(tt[c2], Wh2[c2 * 2 + t], o);
        out[g * 2 + t] = o;
    }
}

// ---------------------------------------------------------------- launcher
extern "C" void kernel_launch(void* const* d_in, const int* in_sizes, int n_in,
                              void* d_out, int out_size, void* d_ws, size_t ws_size,
                              hipStream_t stream) {
    const float* x   = (const float*)d_in[0];
    const int*   ei  = (const int*)d_in[1];
    const int*   row = ei;        // edge_index[0] = src
    const int*   col = ei + NE;   // edge_index[1] = dst
    const float* u   = (const float*)d_in[2];
    const int*   batch = (const int*)d_in[3];
    const float* W1  = (const float*)d_in[5];
    const float* b1  = (const float*)d_in[6];
    const float* W2  = (const float*)d_in[7];
    const float* b2  = (const float*)d_in[8];
    const float* Wh1 = (const float*)d_in[9];
    const float* bh1 = (const float*)d_in[10];
    const float* Wh2 = (const float*)d_in[11];
    const float* bh2 = (const float*)d_in[12];
    float* out = (float*)d_out;

    char* ws = (char*)d_ws;
    size_t o = 0;
    auto alloc = [&](size_t bytes) -> void* {
        void* p = ws + o;
        o += (bytes + 511) & ~(size_t)511;
        return p;
    };
    unsigned short* Xbf = (unsigned short*)alloc((size_t)NN * 128 * 2);  // also A1 (aliased)
    unsigned short* Hsb = (unsigned short*)alloc((size_t)NN * 128 * 2);  // Hs1 / Hs2
    float* A2f    = (float*)alloc((size_t)NN * 128 * 4);
    int*   deg    = (int*)alloc((size_t)NPAD * 4);
    float* dinv   = (float*)alloc((size_t)NN * 4);
    int*   off    = (int*)alloc((size_t)(NN + 1) * 4);
    int*   cursor = (int*)alloc((size_t)NN * 4);
    int*   bsum   = (int*)alloc((size_t)128 * 4);
    int*   boff   = (int*)alloc((size_t)128 * 4);
    int*   csr_src= (int*)alloc((size_t)NE * 4);
    float* emb    = (float*)alloc((size_t)NG * 128 * 4);
    unsigned short* A1bf = Xbf;  // x cast dead after first GEMM

    // --- normalization + CSR build ---
    k_init_deg<<<cdiv(NPAD, 256), 256, 0, stream>>>(deg);
    k_count<<<cdiv(NE, 256), 256, 0, stream>>>(col, deg);
    k_dinv<<<cdiv(NN, 256), 256, 0, stream>>>(deg, dinv);
    k_scan1<<<98, 256, 0, stream>>>(deg, bsum);
    k_scan2<<<1, 128, 0, stream>>>(bsum, boff, off);
    k_scan3<<<98, 256, 0, stream>>>(deg, boff, off, cursor);
    k_fill<<<cdiv(NE, 256), 256, 0, stream>>>(row, col, cursor, csr_src);

    // --- cast input ---
    k_cast<<<NN * 128 / (256 * 8), 256, 0, stream>>>(x, (uint*)Xbf);

    // --- layer 1 ---
    k_gemm<<<cdiv(NN, 128), 256, 0, stream>>>(Xbf, W1, dinv, Hsb);
    k_agg<true><<<NN / 4, 256, 0, stream>>>((const unsigned int*)Hsb, off, csr_src,
                                            dinv, b1, (void*)A1bf);
    // --- layer 2 ---
    k_gemm<<<cdiv(NN, 128), 256, 0, stream>>>(A1bf, W2, dinv, Hsb);
    k_agg<false><<<NN / 4, 256, 0, stream>>>((const unsigned int*)Hsb, off, csr_src,
                                             dinv, b2, (void*)A2f);

    // --- mean pool + head ---
    k_pool<<<NG, 128, 0, stream>>>(A2f, batch, emb);
    k_head<<<NG, 128, 0, stream>>>(emb, u, Wh1, bh1, Wh2, bh2, out);
}

// Round 4
// 545.825 us; speedup vs baseline: 1.8341x; 1.3076x over previous
//
#include <hip/hip_runtime.h>
#include <hip/hip_bf16.h>

#define NN 100000   // nodes
#define NE 1600000  // edges
#define NG 1000     // graphs
#define NPAD (98 * 1024)  // NN rounded up to 98 scan blocks of 1024

typedef short short8 __attribute__((ext_vector_type(8)));
typedef float f32x4 __attribute__((ext_vector_type(4)));

static inline int cdiv(int a, int b) { return (a + b - 1) / b; }

// f32 -> bf16 (RNE) and helpers
__device__ __forceinline__ unsigned short f2b(float f) {
    unsigned int u = __float_as_uint(f);
    u += 0x7fff + ((u >> 16) & 1);
    return (unsigned short)(u >> 16);
}
__device__ __forceinline__ unsigned int pack2(float lo, float hi) {
    return (unsigned int)f2b(lo) | ((unsigned int)f2b(hi) << 16);
}
__device__ __forceinline__ float bf_lo(unsigned int v) { return __uint_as_float(v << 16); }
__device__ __forceinline__ float bf_hi(unsigned int v) { return __uint_as_float(v & 0xffff0000u); }

// ---------------------------------------------------------------- degree
__global__ void k_init_deg(int* __restrict__ deg) {
    int i = blockIdx.x * 256 + threadIdx.x;
    if (i < NPAD) deg[i] = 0;
}

__global__ void k_count(const int* __restrict__ col, int* __restrict__ deg) {
    int e = blockIdx.x * 256 + threadIdx.x;
    if (e < NE) atomicAdd(&deg[col[e]], 1);
}

__global__ void k_dinv(const int* __restrict__ deg, float* __restrict__ dinv) {
    int i = blockIdx.x * 256 + threadIdx.x;
    if (i < NN) dinv[i] = rsqrtf((float)(deg[i] + 1));  // +1 self-loop
}

// ------------------------------------------------- hierarchical CSR scan
__global__ __launch_bounds__(256) void k_scan1(const int* __restrict__ deg,
                                               int* __restrict__ bsum) {
    int t = threadIdx.x;
    int4 v = *(const int4*)(deg + blockIdx.x * 1024 + t * 4);
    int s = v.x + v.y + v.z + v.w;
    for (int d = 32; d; d >>= 1) s += __shfl_down(s, d);
    __shared__ int ws[4];
    if ((t & 63) == 0) ws[t >> 6] = s;
    __syncthreads();
    if (t == 0) bsum[blockIdx.x] = ws[0] + ws[1] + ws[2] + ws[3];
}

__global__ __launch_bounds__(128) void k_scan2(const int* __restrict__ bsum,
                                               int* __restrict__ boff,
                                               int* __restrict__ off) {
    int t = threadIdx.x;
    int v = (t < 98) ? bsum[t] : 0;
    __shared__ int sh[128];
    sh[t] = v;
    __syncthreads();
    for (int d = 1; d < 128; d <<= 1) {
        int u = (t >= d) ? sh[t - d] : 0;
        __syncthreads();
        sh[t] += u;
        __syncthreads();
    }
    if (t < 98) boff[t] = sh[t] - v;
    if (t == 0) off[NN] = NE;
}

__global__ __launch_bounds__(256) void k_scan3(const int* __restrict__ deg,
                                               const int* __restrict__ boff,
                                               int* __restrict__ off,
                                               int* __restrict__ cursor) {
    int t = threadIdx.x;
    int base = blockIdx.x * 1024 + t * 4;
    int4 v = *(const int4*)(deg + base);
    int tsum = v.x + v.y + v.z + v.w;
    __shared__ int sh[256];
    sh[t] = tsum;
    __syncthreads();
    for (int d = 1; d < 256; d <<= 1) {
        int u = (t >= d) ? sh[t - d] : 0;
        __syncthreads();
        sh[t] += u;
        __syncthreads();
    }
    int run = boff[blockIdx.x] + sh[t] - tsum;
    int o1 = run + v.x, o2 = o1 + v.y, o3 = o2 + v.z;
    if (base < NN)     { off[base]     = run; cursor[base]     = run; }
    if (base + 1 < NN) { off[base + 1] = o1;  cursor[base + 1] = o1;  }
    if (base + 2 < NN) { off[base + 2] = o2;  cursor[base + 2] = o2;  }
    if (base + 3 < NN) { off[base + 3] = o3;  cursor[base + 3] = o3;  }
}

// scatter edges into dst-sorted CSR (src only; norms folded into features)
__global__ void k_fill(const int* __restrict__ row, const int* __restrict__ col,
                       int* __restrict__ cursor, int* __restrict__ csr_src) {
    int e = blockIdx.x * 256 + threadIdx.x;
    if (e < NE) {
        int s = row[e], d = col[e];
        int p = atomicAdd(&cursor[d], 1);
        csr_src[p] = s;
    }
}

// ---------------------------------------------------------------- cast x->bf16
__global__ void k_cast(const float* __restrict__ X, uint* __restrict__ O) {
    int i = blockIdx.x * 256 + threadIdx.x;  // 8 floats each
    const float4* X4 = (const float4*)X;
    float4 v0 = X4[i * 2], v1 = X4[i * 2 + 1];
    uint4 o;
    o.x = pack2(v0.x, v0.y); o.y = pack2(v0.z, v0.w);
    o.z = pack2(v1.x, v1.y); o.w = pack2(v1.z, v1.w);
    ((uint4*)O)[i] = o;
}

// ---------------------------------------------------------------- MFMA GEMM
// Hs[r][c] = dinv[r] * sum_k A[r][k] * W[k][c]   (A bf16, W f32, Hs bf16)
__global__ __launch_bounds__(256) void k_gemm(const unsigned short* __restrict__ A,
                                              const float* __restrict__ W,
                                              const float* __restrict__ dinv,
                                              unsigned short* __restrict__ Hs) {
    __shared__ __align__(16) unsigned short Wt[128 * 128];  // 32 KB
    int t = threadIdx.x;
    {
        const float4* W4 = (const float4*)W;  // 4096 float4
#pragma unroll
        for (int ii = 0; ii < 16; ii++) {
            int idx = t + ii * 256;
            float4 v = W4[idx];
            int k = idx >> 5;         // W row (k index)
            int n0 = (idx & 31) * 4;  // W col (n index)
            float vv[4] = {v.x, v.y, v.z, v.w};
#pragma unroll
            for (int j = 0; j < 4; j++) {
                int n = n0 + j;
                int byte = n * 256 + ((((k >> 3) ^ (n & 15))) << 4) + ((k & 7) << 1);
                *(unsigned short*)((char*)Wt + byte) = f2b(vv[j]);
            }
        }
    }
    __syncthreads();

    int lane = t & 63, wid = t >> 6;
    int n16 = lane & 15, quad = lane >> 4;
    int row_base = blockIdx.x * 128 + wid * 32;

    short8 a[2][4];
#pragma unroll
    for (int rt = 0; rt < 2; rt++) {
        int r = row_base + rt * 16 + n16;
        if (r > NN - 1) r = NN - 1;
        const unsigned short* ap = A + (size_t)r * 128 + quad * 8;
#pragma unroll
        for (int ks = 0; ks < 4; ks++)
            a[rt][ks] = *(const short8*)(ap + ks * 32);
    }

    f32x4 acc[2][8];
#pragma unroll
    for (int rt = 0; rt < 2; rt++)
#pragma unroll
        for (int ct = 0; ct < 8; ct++)
            acc[rt][ct] = (f32x4){0.f, 0.f, 0.f, 0.f};

#pragma unroll
    for (int ks = 0; ks < 4; ks++) {
#pragma unroll
        for (int ct = 0; ct < 8; ct++) {
            short8 b = *(const short8*)((const char*)Wt +
                        (ct * 16 + n16) * 256 + ((((ks << 2) + quad) ^ n16) << 4));
            acc[0][ct] = __builtin_amdgcn_mfma_f32_16x16x32_bf16(a[0][ks], b, acc[0][ct], 0, 0, 0);
            acc[1][ct] = __builtin_amdgcn_mfma_f32_16x16x32_bf16(a[1][ks], b, acc[1][ct], 0, 0, 0);
        }
    }

#pragma unroll
    for (int rt = 0; rt < 2; rt++) {
#pragma unroll
        for (int reg = 0; reg < 4; reg++) {
            int row = row_base + rt * 16 + quad * 4 + reg;
            if (row < NN) {
                float di = dinv[row];
                unsigned short* hp = Hs + (size_t)row * 128 + n16;
#pragma unroll
                for (int ct = 0; ct < 8; ct++)
                    hp[ct * 16] = f2b(acc[rt][ct][reg] * di);
            }
        }
    }
}

// ---------------------------------------------------------------- aggregation
// out[i] = relu( dinv[i] * (Hs[i] + sum_e Hs[src_e]) + bias ), bf16 out.
// one wave per node; 4 subgroups x 16 lanes; subgroup handles one edge,
// lane li holds uint4 = cols li*8..li*8+7. 8 edges (2 gathers) per main iter.
__global__ __launch_bounds__(256) void k_agg(const uint4* __restrict__ H4,
                                             const int* __restrict__ off,
                                             const int* __restrict__ csr_src,
                                             const float* __restrict__ dinv,
                                             const float* __restrict__ bias,
                                             uint4* __restrict__ out4) {
    int node = blockIdx.x * 4 + (threadIdx.x >> 6);
    int lane = threadIdx.x & 63;
    int sub = lane >> 4, li = lane & 15;
    float a0 = 0.f, a1 = 0.f, a2 = 0.f, a3 = 0.f,
          a4 = 0.f, a5 = 0.f, a6 = 0.f, a7 = 0.f;
    if (sub == 0) {  // self term (already dinv-scaled)
        uint4 v = H4[(size_t)node * 16 + li];
        a0 = bf_lo(v.x); a1 = bf_hi(v.x); a2 = bf_lo(v.y); a3 = bf_hi(v.y);
        a4 = bf_lo(v.z); a5 = bf_hi(v.z); a6 = bf_lo(v.w); a7 = bf_hi(v.w);
    }
    int e0 = off[node], e1 = off[node + 1];
    int e = e0;
    for (; e + 8 <= e1; e += 8) {
        int sA = csr_src[e + sub];
        int sB = csr_src[e + 4 + sub];
        uint4 wA = H4[(size_t)sA * 16 + li];
        uint4 wB = H4[(size_t)sB * 16 + li];
        a0 += bf_lo(wA.x) + bf_lo(wB.x); a1 += bf_hi(wA.x) + bf_hi(wB.x);
        a2 += bf_lo(wA.y) + bf_lo(wB.y); a3 += bf_hi(wA.y) + bf_hi(wB.y);
        a4 += bf_lo(wA.z) + bf_lo(wB.z); a5 += bf_hi(wA.z) + bf_hi(wB.z);
        a6 += bf_lo(wA.w) + bf_lo(wB.w); a7 += bf_hi(wA.w) + bf_hi(wB.w);
    }
    for (; e < e1; e += 4) {
        int ee = e + sub;
        if (ee < e1) {
            int s = csr_src[ee];
            uint4 w = H4[(size_t)s * 16 + li];
            a0 += bf_lo(w.x); a1 += bf_hi(w.x);
            a2 += bf_lo(w.y); a3 += bf_hi(w.y);
            a4 += bf_lo(w.z); a5 += bf_hi(w.z);
            a6 += bf_lo(w.w); a7 += bf_hi(w.w);
        }
    }
    // butterfly reduce across the 4 subgroups (xor 16, 32)
#pragma unroll
    for (int d = 16; d <= 32; d <<= 1) {
        a0 += __shfl_xor(a0, d); a1 += __shfl_xor(a1, d);
        a2 += __shfl_xor(a2, d); a3 += __shfl_xor(a3, d);
        a4 += __shfl_xor(a4, d); a5 += __shfl_xor(a5, d);
        a6 += __shfl_xor(a6, d); a7 += __shfl_xor(a7, d);
    }
    if (sub == 0) {
        float di = dinv[node];
        const float4* b4 = (const float4*)bias;
        float4 bA = b4[li * 2], bB = b4[li * 2 + 1];
        float r0 = fmaxf(fmaf(di, a0, bA.x), 0.f);
        float r1 = fmaxf(fmaf(di, a1, bA.y), 0.f);
        float r2 = fmaxf(fmaf(di, a2, bA.z), 0.f);
        float r3 = fmaxf(fmaf(di, a3, bA.w), 0.f);
        float r4 = fmaxf(fmaf(di, a4, bB.x), 0.f);
        float r5 = fmaxf(fmaf(di, a5, bB.y), 0.f);
        float r6 = fmaxf(fmaf(di, a6, bB.z), 0.f);
        float r7 = fmaxf(fmaf(di, a7, bB.w), 0.f);
        uint4 o;
        o.x = pack2(r0, r1); o.y = pack2(r2, r3);
        o.z = pack2(r4, r5); o.w = pack2(r6, r7);
        out4[(size_t)node * 16 + li] = o;
    }
}

// ---------------------------------------------------------------- mean pool
// reads bf16 activations, accumulates f32
__global__ __launch_bounds__(128) void k_pool(const unsigned short* __restrict__ A,
                                              const int* __restrict__ batch,
                                              float* __restrict__ emb) {
    int g = blockIdx.x;
    int c = threadIdx.x;
    int lo = 0, hi = NN;
    while (lo < hi) { int m = (lo + hi) >> 1; if (batch[m] < g) lo = m + 1; else hi = m; }
    int start = lo;
    hi = NN;
    while (lo < hi) { int m = (lo + hi) >> 1; if (batch[m] < g + 1) lo = m + 1; else hi = m; }
    int end = lo;
    float s = 0.f;
    for (int i = start; i < end; i++)
        s += __uint_as_float((unsigned int)A[(size_t)i * 128 + c] << 16);
    int cnt = end - start;
    emb[g * 128 + c] = s / (float)max(cnt, 1);
}

// ---------------------------------------------------------------- head MLP
__global__ __launch_bounds__(128) void k_head(const float* __restrict__ emb,
                                              const float* __restrict__ u,
                                              const float* __restrict__ Wh1,
                                              const float* __restrict__ bh1,
                                              const float* __restrict__ Wh2,
                                              const float* __restrict__ bh2,
                                              float* __restrict__ out) {
    __shared__ float hc[192];
    __shared__ float tt[128];
    int g = blockIdx.x, t = threadIdx.x;
    hc[t] = emb[g * 128 + t];
    if (t < 64) hc[128 + t] = u[g * 64 + t];
    __syncthreads();
    float acc = bh1[t];
    for (int k = 0; k < 192; k++) acc = fmaf(hc[k], Wh1[k * 128 + t], acc);
    tt[t] = fmaxf(acc, 0.f);
    __syncthreads();
    if (t < 2) {
        float o = bh2[t];
        for (int c2 = 0; c2 < 128; c2++) o = fmaf(tt[c2], Wh2[c2 * 2 + t], o);
        out[g * 2 + t] = o;
    }
}

// ---------------------------------------------------------------- launcher
extern "C" void kernel_launch(void* const* d_in, const int* in_sizes, int n_in,
                              void* d_out, int out_size, void* d_ws, size_t ws_size,
                              hipStream_t stream) {
    const float* x   = (const float*)d_in[0];
    const int*   ei  = (const int*)d_in[1];
    const int*   row = ei;        // edge_index[0] = src
    const int*   col = ei + NE;   // edge_index[1] = dst
    const float* u   = (const float*)d_in[2];
    const int*   batch = (const int*)d_in[3];
    const float* W1  = (const float*)d_in[5];
    const float* b1  = (const float*)d_in[6];
    const float* W2  = (const float*)d_in[7];
    const float* b2  = (const float*)d_in[8];
    const float* Wh1 = (const float*)d_in[9];
    const float* bh1 = (const float*)d_in[10];
    const float* Wh2 = (const float*)d_in[11];
    const float* bh2 = (const float*)d_in[12];
    float* out = (float*)d_out;

    char* ws = (char*)d_ws;
    size_t o = 0;
    auto alloc = [&](size_t bytes) -> void* {
        void* p = ws + o;
        o += (bytes + 511) & ~(size_t)511;
        return p;
    };
    unsigned short* Xbf = (unsigned short*)alloc((size_t)NN * 128 * 2);  // also A1 (aliased)
    unsigned short* Hsb = (unsigned short*)alloc((size_t)NN * 128 * 2);  // Hs1 / Hs2
    unsigned short* A2b = (unsigned short*)alloc((size_t)NN * 128 * 2);  // layer-2 activations
    int*   deg    = (int*)alloc((size_t)NPAD * 4);
    float* dinv   = (float*)alloc((size_t)NN * 4);
    int*   off    = (int*)alloc((size_t)(NN + 1) * 4);
    int*   cursor = (int*)alloc((size_t)NN * 4);
    int*   bsum   = (int*)alloc((size_t)128 * 4);
    int*   boff   = (int*)alloc((size_t)128 * 4);
    int*   csr_src= (int*)alloc((size_t)NE * 4);
    float* emb    = (float*)alloc((size_t)NG * 128 * 4);
    unsigned short* A1bf = Xbf;  // x cast dead after first GEMM

    // --- normalization + CSR build ---
    k_init_deg<<<cdiv(NPAD, 256), 256, 0, stream>>>(deg);
    k_count<<<cdiv(NE, 256), 256, 0, stream>>>(col, deg);
    k_dinv<<<cdiv(NN, 256), 256, 0, stream>>>(deg, dinv);
    k_scan1<<<98, 256, 0, stream>>>(deg, bsum);
    k_scan2<<<1, 128, 0, stream>>>(bsum, boff, off);
    k_scan3<<<98, 256, 0, stream>>>(deg, boff, off, cursor);
    k_fill<<<cdiv(NE, 256), 256, 0, stream>>>(row, col, cursor, csr_src);

    // --- cast input ---
    k_cast<<<NN * 128 / (256 * 8), 256, 0, stream>>>(x, (uint*)Xbf);

    // --- layer 1 ---
    k_gemm<<<cdiv(NN, 128), 256, 0, stream>>>(Xbf, W1, dinv, Hsb);
    k_agg<<<NN / 4, 256, 0, stream>>>((const uint4*)Hsb, off, csr_src,
                                      dinv, b1, (uint4*)A1bf);
    // --- layer 2 ---
    k_gemm<<<cdiv(NN, 128), 256, 0, stream>>>(A1bf, W2, dinv, Hsb);
    k_agg<<<NN / 4, 256, 0, stream>>>((const uint4*)Hsb, off, csr_src,
                                      dinv, b2, (uint4*)A2b);

    // --- mean pool + head ---
    k_pool<<<NG, 128, 0, stream>>>(A2b, batch, emb);
    k_head<<<NG, 128, 0, stream>>>(emb, u, Wh1, bh1, Wh2, bh2, out);
}

// Round 5
// 469.264 us; speedup vs baseline: 2.1334x; 1.1632x over previous
//
#include <hip/hip_runtime.h>
#include <hip/hip_bf16.h>

#define NN 100000   // nodes
#define NE 1600000  // edges
#define NG 1000     // graphs
#define NBK 196     // dst buckets of 512 nodes (196*512 >= NN)
#define BSH 9       // bucket shift

typedef short short8 __attribute__((ext_vector_type(8)));
typedef float f32x4 __attribute__((ext_vector_type(4)));

static inline int cdiv(int a, int b) { return (a + b - 1) / b; }

// f32 -> bf16 (RNE) and helpers
__device__ __forceinline__ unsigned short f2b(float f) {
    unsigned int u = __float_as_uint(f);
    u += 0x7fff + ((u >> 16) & 1);
    return (unsigned short)(u >> 16);
}
__device__ __forceinline__ unsigned int pack2(float lo, float hi) {
    return (unsigned int)f2b(lo) | ((unsigned int)f2b(hi) << 16);
}
__device__ __forceinline__ float bf_lo(unsigned int v) { return __uint_as_float(v << 16); }
__device__ __forceinline__ float bf_hi(unsigned int v) { return __uint_as_float(v & 0xffff0000u); }

// -------------------------------------------------------- bucket histogram
__global__ __launch_bounds__(256) void k_bhist(const int* __restrict__ col,
                                               int* __restrict__ bhist) {
    __shared__ int h[NBK];
    int t = threadIdx.x;
    if (t < NBK) h[t] = 0;
    __syncthreads();
    for (int i = blockIdx.x * 256 + t; i < NE; i += gridDim.x * 256)
        atomicAdd(&h[col[i] >> BSH], 1);
    __syncthreads();
    if (t < NBK) atomicAdd(&bhist[t], h[t]);
}

// -------------------------------------------------------- bucket scan
__global__ __launch_bounds__(256) void k_bscan(const int* __restrict__ bhist,
                                               int* __restrict__ bbase,
                                               int* __restrict__ gcur) {
    int t = threadIdx.x;
    int v = (t < NBK) ? bhist[t] : 0;
    __shared__ int sh[256];
    sh[t] = v;
    __syncthreads();
    for (int d = 1; d < 256; d <<= 1) {
        int u = (t >= d) ? sh[t - d] : 0;
        __syncthreads();
        sh[t] += u;
        __syncthreads();
    }
    int ex = sh[t] - v;  // exclusive prefix
    if (t <= NBK) bbase[t] = ex;
    if (t < NBK) gcur[t] = ex;
}

// -------------------------------------------------------- LDS-staged binning
// scatter packed (dlocal<<17 | src) into per-bucket regions of tmp,
// flushing in 16-entry (64B) chunks to kill write amplification.
__global__ __launch_bounds__(256) void k_bin(const int* __restrict__ row,
                                             const int* __restrict__ col,
                                             int* __restrict__ gcur,
                                             unsigned int* __restrict__ tmp) {
    __shared__ unsigned int stage[NBK * 32];
    __shared__ int scnt[NBK];
    int t = threadIdx.x;
    if (t < NBK) scnt[t] = 0;
    __syncthreads();
    const int per = NE / 128;  // 12500
    int base = blockIdx.x * per;
    int end = base + per;
    for (int it = 0; it < 49; it++) {
        int i = base + it * 256 + t;
        if (i < end) {
            int s = row[i], d = col[i];
            int b = d >> BSH;
            unsigned int entry = ((unsigned int)(d & 511) << 17) | (unsigned int)s;
            int pos = atomicAdd(&scnt[b], 1);
            if (pos < 32) stage[b * 32 + pos] = entry;
            else { int gp = atomicAdd(&gcur[b], 1); tmp[gp] = entry; }  // rare overflow
        }
        __syncthreads();
        if (t < NBK) {
            int c = min(scnt[t], 32);
            int nf = c & ~15;
            if (nf) {
                int gp = atomicAdd(&gcur[t], nf);
                for (int q = 0; q < nf; q++) tmp[gp + q] = stage[t * 32 + q];
                int rem = c - nf;
                for (int q = 0; q < rem; q++) stage[t * 32 + q] = stage[t * 32 + nf + q];
                scnt[t] = rem;
            } else {
                scnt[t] = c;
            }
        }
        __syncthreads();
    }
    if (t < NBK) {  // final flush
        int c = min(scnt[t], 32);
        if (c) {
            int gp = atomicAdd(&gcur[t], c);
            for (int q = 0; q < c; q++) tmp[gp + q] = stage[t * 32 + q];
        }
    }
}

// -------------------------------------------------------- per-bucket CSR
// one block per bucket: per-dst degree count, local scan -> off/dinv,
// then permute entries into csr_src (writes confined to this bucket's window).
__global__ __launch_bounds__(256) void k_bucket(const unsigned int* __restrict__ tmp,
                                                const int* __restrict__ bbase,
                                                int* __restrict__ off,
                                                float* __restrict__ dinv,
                                                int* __restrict__ csr_src) {
    __shared__ int cnt[512];
    __shared__ int loff[512];
    __shared__ int sh[256];
    int b = blockIdx.x, t = threadIdx.x;
    int j0 = b << BSH;
    int nd = min(512, NN - j0);
    int rb = bbase[b], re = bbase[b + 1], m = re - rb;
    cnt[t] = 0; cnt[t + 256] = 0;
    __syncthreads();
    for (int i = t; i < m; i += 256)
        atomicAdd(&cnt[tmp[rb + i] >> 17], 1);
    __syncthreads();
    int a0 = cnt[2 * t], a1 = cnt[2 * t + 1];
    int ts = a0 + a1;
    sh[t] = ts;
    __syncthreads();
    for (int d = 1; d < 256; d <<= 1) {
        int u = (t >= d) ? sh[t - d] : 0;
        __syncthreads();
        sh[t] += u;
        __syncthreads();
    }
    int ex = sh[t] - ts;
    loff[2 * t] = ex;
    loff[2 * t + 1] = ex + a0;
    __syncthreads();
    for (int j = t; j < nd; j += 256) {
        int o = rb + loff[j];
        off[j0 + j] = o;
        dinv[j0 + j] = rsqrtf((float)(cnt[j] + 1));  // +1 self-loop
        cnt[j] = o;  // becomes cursor
    }
    if (b == NBK - 1 && t == 0) off[NN] = re;
    __syncthreads();
    for (int i = t; i < m; i += 256) {
        unsigned int e = tmp[rb + i];
        int d = e >> 17;
        int s = (int)(e & 0x1FFFFu);
        int p = atomicAdd(&cnt[d], 1);
        csr_src[p] = s;
    }
}

// ---------------------------------------------------------------- cast x->bf16
__global__ void k_cast(const float* __restrict__ X, uint* __restrict__ O) {
    int i = blockIdx.x * 256 + threadIdx.x;  // 8 floats each
    const float4* X4 = (const float4*)X;
    float4 v0 = X4[i * 2], v1 = X4[i * 2 + 1];
    uint4 o;
    o.x = pack2(v0.x, v0.y); o.y = pack2(v0.z, v0.w);
    o.z = pack2(v1.x, v1.y); o.w = pack2(v1.z, v1.w);
    ((uint4*)O)[i] = o;
}

// ---------------------------------------------------------------- MFMA GEMM
// Hs[r][c] = dinv[r] * sum_k A[r][k] * W[k][c]   (A bf16, W f32, Hs bf16)
__global__ __launch_bounds__(256) void k_gemm(const unsigned short* __restrict__ A,
                                              const float* __restrict__ W,
                                              const float* __restrict__ dinv,
                                              unsigned short* __restrict__ Hs) {
    __shared__ __align__(16) unsigned short Wt[128 * 128];  // 32 KB
    int t = threadIdx.x;
    {
        const float4* W4 = (const float4*)W;  // 4096 float4
#pragma unroll
        for (int ii = 0; ii < 16; ii++) {
            int idx = t + ii * 256;
            float4 v = W4[idx];
            int k = idx >> 5;
            int n0 = (idx & 31) * 4;
            float vv[4] = {v.x, v.y, v.z, v.w};
#pragma unroll
            for (int j = 0; j < 4; j++) {
                int n = n0 + j;
                int byte = n * 256 + ((((k >> 3) ^ (n & 15))) << 4) + ((k & 7) << 1);
                *(unsigned short*)((char*)Wt + byte) = f2b(vv[j]);
            }
        }
    }
    __syncthreads();

    int lane = t & 63, wid = t >> 6;
    int n16 = lane & 15, quad = lane >> 4;
    int row_base = blockIdx.x * 128 + wid * 32;

    short8 a[2][4];
#pragma unroll
    for (int rt = 0; rt < 2; rt++) {
        int r = row_base + rt * 16 + n16;
        if (r > NN - 1) r = NN - 1;
        const unsigned short* ap = A + (size_t)r * 128 + quad * 8;
#pragma unroll
        for (int ks = 0; ks < 4; ks++)
            a[rt][ks] = *(const short8*)(ap + ks * 32);
    }

    f32x4 acc[2][8];
#pragma unroll
    for (int rt = 0; rt < 2; rt++)
#pragma unroll
        for (int ct = 0; ct < 8; ct++)
            acc[rt][ct] = (f32x4){0.f, 0.f, 0.f, 0.f};

#pragma unroll
    for (int ks = 0; ks < 4; ks++) {
#pragma unroll
        for (int ct = 0; ct < 8; ct++) {
            short8 b = *(const short8*)((const char*)Wt +
                        (ct * 16 + n16) * 256 + ((((ks << 2) + quad) ^ n16) << 4));
            acc[0][ct] = __builtin_amdgcn_mfma_f32_16x16x32_bf16(a[0][ks], b, acc[0][ct], 0, 0, 0);
            acc[1][ct] = __builtin_amdgcn_mfma_f32_16x16x32_bf16(a[1][ks], b, acc[1][ct], 0, 0, 0);
        }
    }

#pragma unroll
    for (int rt = 0; rt < 2; rt++) {
#pragma unroll
        for (int reg = 0; reg < 4; reg++) {
            int row = row_base + rt * 16 + quad * 4 + reg;
            if (row < NN) {
                float di = dinv[row];
                unsigned short* hp = Hs + (size_t)row * 128 + n16;
#pragma unroll
                for (int ct = 0; ct < 8; ct++)
                    hp[ct * 16] = f2b(acc[rt][ct][reg] * di);
            }
        }
    }
}

// ---------------------------------------------------------------- aggregation
// out[i] = relu( dinv[i] * (Hs[i] + sum_e Hs[src_e]) + bias ), bf16 out.
// 4 subgroups x 16 lanes per wave; 16 edges (4 independent gathers) per iter.
__global__ __launch_bounds__(256) void k_agg(const uint4* __restrict__ H4,
                                             const int* __restrict__ off,
                                             const int* __restrict__ csr_src,
                                             const float* __restrict__ dinv,
                                             const float* __restrict__ bias,
                                             uint4* __restrict__ out4) {
    int node = blockIdx.x * 4 + (threadIdx.x >> 6);
    int lane = threadIdx.x & 63;
    int sub = lane >> 4, li = lane & 15;
    float a0 = 0.f, a1 = 0.f, a2 = 0.f, a3 = 0.f,
          a4 = 0.f, a5 = 0.f, a6 = 0.f, a7 = 0.f;
    if (sub == 0) {  // self term (already dinv-scaled)
        uint4 v = H4[(size_t)node * 16 + li];
        a0 = bf_lo(v.x); a1 = bf_hi(v.x); a2 = bf_lo(v.y); a3 = bf_hi(v.y);
        a4 = bf_lo(v.z); a5 = bf_hi(v.z); a6 = bf_lo(v.w); a7 = bf_hi(v.w);
    }
    int e0 = off[node], e1 = off[node + 1];
    int e = e0;
    for (; e + 16 <= e1; e += 16) {
        int s0 = csr_src[e + sub];
        int s1 = csr_src[e + 4 + sub];
        int s2 = csr_src[e + 8 + sub];
        int s3 = csr_src[e + 12 + sub];
        uint4 w0 = H4[(size_t)s0 * 16 + li];
        uint4 w1 = H4[(size_t)s1 * 16 + li];
        uint4 w2 = H4[(size_t)s2 * 16 + li];
        uint4 w3 = H4[(size_t)s3 * 16 + li];
        a0 += (bf_lo(w0.x) + bf_lo(w1.x)) + (bf_lo(w2.x) + bf_lo(w3.x));
        a1 += (bf_hi(w0.x) + bf_hi(w1.x)) + (bf_hi(w2.x) + bf_hi(w3.x));
        a2 += (bf_lo(w0.y) + bf_lo(w1.y)) + (bf_lo(w2.y) + bf_lo(w3.y));
        a3 += (bf_hi(w0.y) + bf_hi(w1.y)) + (bf_hi(w2.y) + bf_hi(w3.y));
        a4 += (bf_lo(w0.z) + bf_lo(w1.z)) + (bf_lo(w2.z) + bf_lo(w3.z));
        a5 += (bf_hi(w0.z) + bf_hi(w1.z)) + (bf_hi(w2.z) + bf_hi(w3.z));
        a6 += (bf_lo(w0.w) + bf_lo(w1.w)) + (bf_lo(w2.w) + bf_lo(w3.w));
        a7 += (bf_hi(w0.w) + bf_hi(w1.w)) + (bf_hi(w2.w) + bf_hi(w3.w));
    }
    for (; e + 8 <= e1; e += 8) {
        int sA = csr_src[e + sub];
        int sB = csr_src[e + 4 + sub];
        uint4 wA = H4[(size_t)sA * 16 + li];
        uint4 wB = H4[(size_t)sB * 16 + li];
        a0 += bf_lo(wA.x) + bf_lo(wB.x); a1 += bf_hi(wA.x) + bf_hi(wB.x);
        a2 += bf_lo(wA.y) + bf_lo(wB.y); a3 += bf_hi(wA.y) + bf_hi(wB.y);
        a4 += bf_lo(wA.z) + bf_lo(wB.z); a5 += bf_hi(wA.z) + bf_hi(wB.z);
        a6 += bf_lo(wA.w) + bf_lo(wB.w); a7 += bf_hi(wA.w) + bf_hi(wB.w);
    }
    for (; e < e1; e += 4) {
        int ee = e + sub;
        if (ee < e1) {
            int s = csr_src[ee];
            uint4 w = H4[(size_t)s * 16 + li];
            a0 += bf_lo(w.x); a1 += bf_hi(w.x);
            a2 += bf_lo(w.y); a3 += bf_hi(w.y);
            a4 += bf_lo(w.z); a5 += bf_hi(w.z);
            a6 += bf_lo(w.w); a7 += bf_hi(w.w);
        }
    }
#pragma unroll
    for (int d = 16; d <= 32; d <<= 1) {
        a0 += __shfl_xor(a0, d); a1 += __shfl_xor(a1, d);
        a2 += __shfl_xor(a2, d); a3 += __shfl_xor(a3, d);
        a4 += __shfl_xor(a4, d); a5 += __shfl_xor(a5, d);
        a6 += __shfl_xor(a6, d); a7 += __shfl_xor(a7, d);
    }
    if (sub == 0) {
        float di = dinv[node];
        const float4* b4 = (const float4*)bias;
        float4 bA = b4[li * 2], bB = b4[li * 2 + 1];
        float r0 = fmaxf(fmaf(di, a0, bA.x), 0.f);
        float r1 = fmaxf(fmaf(di, a1, bA.y), 0.f);
        float r2 = fmaxf(fmaf(di, a2, bA.z), 0.f);
        float r3 = fmaxf(fmaf(di, a3, bA.w), 0.f);
        float r4 = fmaxf(fmaf(di, a4, bB.x), 0.f);
        float r5 = fmaxf(fmaf(di, a5, bB.y), 0.f);
        float r6 = fmaxf(fmaf(di, a6, bB.z), 0.f);
        float r7 = fmaxf(fmaf(di, a7, bB.w), 0.f);
        uint4 o;
        o.x = pack2(r0, r1); o.y = pack2(r2, r3);
        o.z = pack2(r4, r5); o.w = pack2(r6, r7);
        out4[(size_t)node * 16 + li] = o;
    }
}

// ---------------------------------------------------------------- mean pool
__global__ __launch_bounds__(128) void k_pool(const unsigned short* __restrict__ A,
                                              const int* __restrict__ batch,
                                              float* __restrict__ emb) {
    int g = blockIdx.x;
    int c = threadIdx.x;
    int lo = 0, hi = NN;
    while (lo < hi) { int m = (lo + hi) >> 1; if (batch[m] < g) lo = m + 1; else hi = m; }
    int start = lo;
    hi = NN;
    while (lo < hi) { int m = (lo + hi) >> 1; if (batch[m] < g + 1) lo = m + 1; else hi = m; }
    int end = lo;
    float s = 0.f;
    for (int i = start; i < end; i++)
        s += __uint_as_float((unsigned int)A[(size_t)i * 128 + c] << 16);
    int cnt = end - start;
    emb[g * 128 + c] = s / (float)max(cnt, 1);
}

// ---------------------------------------------------------------- head MLP
__global__ __launch_bounds__(128) void k_head(const float* __restrict__ emb,
                                              const float* __restrict__ u,
                                              const float* __restrict__ Wh1,
                                              const float* __restrict__ bh1,
                                              const float* __restrict__ Wh2,
                                              const float* __restrict__ bh2,
                                              float* __restrict__ out) {
    __shared__ float hc[192];
    __shared__ float tt[128];
    int g = blockIdx.x, t = threadIdx.x;
    hc[t] = emb[g * 128 + t];
    if (t < 64) hc[128 + t] = u[g * 64 + t];
    __syncthreads();
    float acc = bh1[t];
    for (int k = 0; k < 192; k++) acc = fmaf(hc[k], Wh1[k * 128 + t], acc);
    tt[t] = fmaxf(acc, 0.f);
    __syncthreads();
    if (t < 2) {
        float o = bh2[t];
        for (int c2 = 0; c2 < 128; c2++) o = fmaf(tt[c2], Wh2[c2 * 2 + t], o);
        out[g * 2 + t] = o;
    }
}

// ---------------------------------------------------------------- launcher
extern "C" void kernel_launch(void* const* d_in, const int* in_sizes, int n_in,
                              void* d_out, int out_size, void* d_ws, size_t ws_size,
                              hipStream_t stream) {
    const float* x   = (const float*)d_in[0];
    const int*   ei  = (const int*)d_in[1];
    const int*   row = ei;        // edge_index[0] = src
    const int*   col = ei + NE;   // edge_index[1] = dst
    const float* u   = (const float*)d_in[2];
    const int*   batch = (const int*)d_in[3];
    const float* W1  = (const float*)d_in[5];
    const float* b1  = (const float*)d_in[6];
    const float* W2  = (const float*)d_in[7];
    const float* b2  = (const float*)d_in[8];
    const float* Wh1 = (const float*)d_in[9];
    const float* bh1 = (const float*)d_in[10];
    const float* Wh2 = (const float*)d_in[11];
    const float* bh2 = (const float*)d_in[12];
    float* out = (float*)d_out;

    char* ws = (char*)d_ws;
    size_t o = 0;
    auto alloc = [&](size_t bytes) -> void* {
        void* p = ws + o;
        o += (bytes + 511) & ~(size_t)511;
        return p;
    };
    unsigned short* Xbf = (unsigned short*)alloc((size_t)NN * 128 * 2);  // also A1 (aliased)
    unsigned short* Hsb = (unsigned short*)alloc((size_t)NN * 128 * 2);
    unsigned short* A2b = (unsigned short*)alloc((size_t)NN * 128 * 2);
    float* dinv   = (float*)alloc((size_t)NN * 4);
    int*   off    = (int*)alloc((size_t)(NN + 1) * 4);
    int*   csr_src= (int*)alloc((size_t)NE * 4);
    unsigned int* tmp = (unsigned int*)alloc((size_t)NE * 4);
    int*   bhist  = (int*)alloc((size_t)256 * 4);
    int*   bbase  = (int*)alloc((size_t)256 * 4);
    int*   gcur   = (int*)alloc((size_t)256 * 4);
    float* emb    = (float*)alloc((size_t)NG * 128 * 4);
    unsigned short* A1bf = Xbf;

    // --- CSR build via locality-aware binning ---
    hipMemsetAsync(bhist, 0, NBK * 4, stream);
    k_bhist<<<512, 256, 0, stream>>>(col, bhist);
    k_bscan<<<1, 256, 0, stream>>>(bhist, bbase, gcur);
    k_bin<<<128, 256, 0, stream>>>(row, col, gcur, tmp);
    k_bucket<<<NBK, 256, 0, stream>>>(tmp, bbase, off, dinv, csr_src);

    // --- cast input ---
    k_cast<<<NN * 128 / (256 * 8), 256, 0, stream>>>(x, (uint*)Xbf);

    // --- layer 1 ---
    k_gemm<<<cdiv(NN, 128), 256, 0, stream>>>(Xbf, W1, dinv, Hsb);
    k_agg<<<NN / 4, 256, 0, stream>>>((const uint4*)Hsb, off, csr_src,
                                      dinv, b1, (uint4*)A1bf);
    // --- layer 2 ---
    k_gemm<<<cdiv(NN, 128), 256, 0, stream>>>(A1bf, W2, dinv, Hsb);
    k_agg<<<NN / 4, 256, 0, stream>>>((const uint4*)Hsb, off, csr_src,
                                      dinv, b2, (uint4*)A2b);

    // --- mean pool + head ---
    k_pool<<<NG, 128, 0, stream>>>(A2b, batch, emb);
    k_head<<<NG, 128, 0, stream>>>(emb, u, Wh1, bh1, Wh2, bh2, out);
}

// Round 6
// 383.694 us; speedup vs baseline: 2.6092x; 1.2230x over previous
//
#include <hip/hip_runtime.h>
#include <hip/hip_bf16.h>

#define NN 100000   // nodes
#define NE 1600000  // edges
#define NG 1000     // graphs
#define NBK 196     // dst buckets of 512 nodes (196*512 >= NN)
#define BSH 9       // bucket shift
#define SLOT 10240  // slack region per bucket in tmp (mean load 8192, sigma~90)

typedef short short8 __attribute__((ext_vector_type(8)));
typedef float f32x4 __attribute__((ext_vector_type(4)));

static inline int cdiv(int a, int b) { return (a + b - 1) / b; }

// f32 -> bf16 (RNE) and helpers
__device__ __forceinline__ unsigned short f2b(float f) {
    unsigned int u = __float_as_uint(f);
    u += 0x7fff + ((u >> 16) & 1);
    return (unsigned short)(u >> 16);
}
__device__ __forceinline__ unsigned int pack2(float lo, float hi) {
    return (unsigned int)f2b(lo) | ((unsigned int)f2b(hi) << 16);
}
__device__ __forceinline__ float bf_lo(unsigned int v) { return __uint_as_float(v << 16); }
__device__ __forceinline__ float bf_hi(unsigned int v) { return __uint_as_float(v & 0xffff0000u); }

// -------------------------------------------------------- cursor init
__global__ __launch_bounds__(256) void k_ginit(int* __restrict__ gcur) {
    int t = threadIdx.x;
    if (t < NBK) gcur[t] = t * SLOT;
}

// -------------------------------------------------------- two-phase binning
// 400 blocks x 4000 edges. Phase 1: LDS bucket count. Reserve contiguous
// chunk per (block,bucket) via one global atomic. Phase 2: direct scatter.
__global__ __launch_bounds__(256) void k_bin2(const int* __restrict__ row,
                                              const int* __restrict__ col,
                                              int* __restrict__ gcur,
                                              unsigned int* __restrict__ tmp) {
    __shared__ int cnt[NBK];
    __shared__ int gbase[NBK];
    int t = threadIdx.x;
    if (t < NBK) cnt[t] = 0;
    __syncthreads();
    const int q0 = blockIdx.x * 1000;  // int4 index base (4000 edges)
    const int4* col4 = (const int4*)col;
    const int4* row4 = (const int4*)row;
#pragma unroll
    for (int it = 0; it < 4; it++) {
        int idx = it * 256 + t;
        if (idx < 1000) {
            int4 c = col4[q0 + idx];
            atomicAdd(&cnt[c.x >> BSH], 1);
            atomicAdd(&cnt[c.y >> BSH], 1);
            atomicAdd(&cnt[c.z >> BSH], 1);
            atomicAdd(&cnt[c.w >> BSH], 1);
        }
    }
    __syncthreads();
    if (t < NBK) {
        gbase[t] = atomicAdd(&gcur[t], cnt[t]);
        cnt[t] = 0;  // becomes local cursor
    }
    __syncthreads();
#pragma unroll
    for (int it = 0; it < 4; it++) {
        int idx = it * 256 + t;
        if (idx < 1000) {
            int4 c = col4[q0 + idx];
            int4 r = row4[q0 + idx];
            int d, s, b, p;
            d = c.x; s = r.x; b = d >> BSH; p = atomicAdd(&cnt[b], 1);
            tmp[gbase[b] + p] = ((unsigned int)(d & 511) << 17) | (unsigned int)s;
            d = c.y; s = r.y; b = d >> BSH; p = atomicAdd(&cnt[b], 1);
            tmp[gbase[b] + p] = ((unsigned int)(d & 511) << 17) | (unsigned int)s;
            d = c.z; s = r.z; b = d >> BSH; p = atomicAdd(&cnt[b], 1);
            tmp[gbase[b] + p] = ((unsigned int)(d & 511) << 17) | (unsigned int)s;
            d = c.w; s = r.w; b = d >> BSH; p = atomicAdd(&cnt[b], 1);
            tmp[gbase[b] + p] = ((unsigned int)(d & 511) << 17) | (unsigned int)s;
        }
    }
}

// -------------------------------------------------------- per-bucket CSR
// one block per bucket: per-dst degree count, local scan -> off/deg/dinv,
// then permute entries into csr_src (writes confined to this bucket's window).
__global__ __launch_bounds__(256) void k_bucket(const unsigned int* __restrict__ tmp,
                                                const int* __restrict__ gcur,
                                                int* __restrict__ off,
                                                int* __restrict__ degw,
                                                float* __restrict__ dinv,
                                                int* __restrict__ csr_src) {
    __shared__ int cnt[512];
    __shared__ int loff[512];
    __shared__ int sh[256];
    int b = blockIdx.x, t = threadIdx.x;
    int j0 = b << BSH;
    int nd = min(512, NN - j0);
    int rb = b * SLOT;
    int m = gcur[b] - rb;
    cnt[t] = 0; cnt[t + 256] = 0;
    __syncthreads();
    for (int i = t; i < m; i += 256)
        atomicAdd(&cnt[tmp[rb + i] >> 17], 1);
    __syncthreads();
    int a0 = cnt[2 * t], a1 = cnt[2 * t + 1];
    int ts = a0 + a1;
    sh[t] = ts;
    __syncthreads();
    for (int d = 1; d < 256; d <<= 1) {
        int u = (t >= d) ? sh[t - d] : 0;
        __syncthreads();
        sh[t] += u;
        __syncthreads();
    }
    int ex = sh[t] - ts;
    loff[2 * t] = ex;
    loff[2 * t + 1] = ex + a0;
    __syncthreads();
    for (int j = t; j < nd; j += 256) {
        int o = rb + loff[j];
        off[j0 + j] = o;
        degw[j0 + j] = cnt[j];
        dinv[j0 + j] = rsqrtf((float)(cnt[j] + 1));  // +1 self-loop
        cnt[j] = o;  // becomes cursor
    }
    __syncthreads();
    for (int i = t; i < m; i += 256) {
        unsigned int e = tmp[rb + i];
        int d = e >> 17;
        int s = (int)(e & 0x1FFFFu);
        int p = atomicAdd(&cnt[d], 1);
        csr_src[p] = s;
    }
}

// ---------------------------------------------------------------- cast x->bf16
__global__ void k_cast(const float* __restrict__ X, uint* __restrict__ O) {
    int i = blockIdx.x * 256 + threadIdx.x;  // 8 floats each
    const float4* X4 = (const float4*)X;
    float4 v0 = X4[i * 2], v1 = X4[i * 2 + 1];
    uint4 o;
    o.x = pack2(v0.x, v0.y); o.y = pack2(v0.z, v0.w);
    o.z = pack2(v1.x, v1.y); o.w = pack2(v1.z, v1.w);
    ((uint4*)O)[i] = o;
}

// ---------------------------------------------------------------- MFMA GEMM
// Hs[r][c] = dinv[r] * sum_k A[r][k] * W[k][c]   (A bf16, W f32, Hs bf16)
__global__ __launch_bounds__(256) void k_gemm(const unsigned short* __restrict__ A,
                                              const float* __restrict__ W,
                                              const float* __restrict__ dinv,
                                              unsigned short* __restrict__ Hs) {
    __shared__ __align__(16) unsigned short Wt[128 * 128];  // 32 KB
    int t = threadIdx.x;
    {
        const float4* W4 = (const float4*)W;  // 4096 float4
#pragma unroll
        for (int ii = 0; ii < 16; ii++) {
            int idx = t + ii * 256;
            float4 v = W4[idx];
            int k = idx >> 5;
            int n0 = (idx & 31) * 4;
            float vv[4] = {v.x, v.y, v.z, v.w};
#pragma unroll
            for (int j = 0; j < 4; j++) {
                int n = n0 + j;
                int byte = n * 256 + ((((k >> 3) ^ (n & 15))) << 4) + ((k & 7) << 1);
                *(unsigned short*)((char*)Wt + byte) = f2b(vv[j]);
            }
        }
    }
    __syncthreads();

    int lane = t & 63, wid = t >> 6;
    int n16 = lane & 15, quad = lane >> 4;
    int row_base = blockIdx.x * 128 + wid * 32;

    short8 a[2][4];
#pragma unroll
    for (int rt = 0; rt < 2; rt++) {
        int r = row_base + rt * 16 + n16;
        if (r > NN - 1) r = NN - 1;
        const unsigned short* ap = A + (size_t)r * 128 + quad * 8;
#pragma unroll
        for (int ks = 0; ks < 4; ks++)
            a[rt][ks] = *(const short8*)(ap + ks * 32);
    }

    f32x4 acc[2][8];
#pragma unroll
    for (int rt = 0; rt < 2; rt++)
#pragma unroll
        for (int ct = 0; ct < 8; ct++)
            acc[rt][ct] = (f32x4){0.f, 0.f, 0.f, 0.f};

#pragma unroll
    for (int ks = 0; ks < 4; ks++) {
#pragma unroll
        for (int ct = 0; ct < 8; ct++) {
            short8 b = *(const short8*)((const char*)Wt +
                        (ct * 16 + n16) * 256 + ((((ks << 2) + quad) ^ n16) << 4));
            acc[0][ct] = __builtin_amdgcn_mfma_f32_16x16x32_bf16(a[0][ks], b, acc[0][ct], 0, 0, 0);
            acc[1][ct] = __builtin_amdgcn_mfma_f32_16x16x32_bf16(a[1][ks], b, acc[1][ct], 0, 0, 0);
        }
    }

#pragma unroll
    for (int rt = 0; rt < 2; rt++) {
#pragma unroll
        for (int reg = 0; reg < 4; reg++) {
            int row = row_base + rt * 16 + quad * 4 + reg;
            if (row < NN) {
                float di = dinv[row];
                unsigned short* hp = Hs + (size_t)row * 128 + n16;
#pragma unroll
                for (int ct = 0; ct < 8; ct++)
                    hp[ct * 16] = f2b(acc[rt][ct][reg] * di);
            }
        }
    }
}

// ---------------------------------------------------------------- aggregation
// out[i] = relu( dinv[i] * (Hs[i] + sum_e Hs[src_e]) + bias ), bf16 out.
// 4 subgroups x 16 lanes per wave; 16 edges (4 independent gathers) per iter.
__global__ __launch_bounds__(256) void k_agg(const uint4* __restrict__ H4,
                                             const int* __restrict__ off,
                                             const int* __restrict__ degw,
                                             const int* __restrict__ csr_src,
                                             const float* __restrict__ dinv,
                                             const float* __restrict__ bias,
                                             uint4* __restrict__ out4) {
    int node = blockIdx.x * 4 + (threadIdx.x >> 6);
    int lane = threadIdx.x & 63;
    int sub = lane >> 4, li = lane & 15;
    float a0 = 0.f, a1 = 0.f, a2 = 0.f, a3 = 0.f,
          a4 = 0.f, a5 = 0.f, a6 = 0.f, a7 = 0.f;
    if (sub == 0) {  // self term (already dinv-scaled)
        uint4 v = H4[(size_t)node * 16 + li];
        a0 = bf_lo(v.x); a1 = bf_hi(v.x); a2 = bf_lo(v.y); a3 = bf_hi(v.y);
        a4 = bf_lo(v.z); a5 = bf_hi(v.z); a6 = bf_lo(v.w); a7 = bf_hi(v.w);
    }
    int e0 = off[node], e1 = e0 + degw[node];
    int e = e0;
    for (; e + 16 <= e1; e += 16) {
        int s0 = csr_src[e + sub];
        int s1 = csr_src[e + 4 + sub];
        int s2 = csr_src[e + 8 + sub];
        int s3 = csr_src[e + 12 + sub];
        uint4 w0 = H4[(size_t)s0 * 16 + li];
        uint4 w1 = H4[(size_t)s1 * 16 + li];
        uint4 w2 = H4[(size_t)s2 * 16 + li];
        uint4 w3 = H4[(size_t)s3 * 16 + li];
        a0 += (bf_lo(w0.x) + bf_lo(w1.x)) + (bf_lo(w2.x) + bf_lo(w3.x));
        a1 += (bf_hi(w0.x) + bf_hi(w1.x)) + (bf_hi(w2.x) + bf_hi(w3.x));
        a2 += (bf_lo(w0.y) + bf_lo(w1.y)) + (bf_lo(w2.y) + bf_lo(w3.y));
        a3 += (bf_hi(w0.y) + bf_hi(w1.y)) + (bf_hi(w2.y) + bf_hi(w3.y));
        a4 += (bf_lo(w0.z) + bf_lo(w1.z)) + (bf_lo(w2.z) + bf_lo(w3.z));
        a5 += (bf_hi(w0.z) + bf_hi(w1.z)) + (bf_hi(w2.z) + bf_hi(w3.z));
        a6 += (bf_lo(w0.w) + bf_lo(w1.w)) + (bf_lo(w2.w) + bf_lo(w3.w));
        a7 += (bf_hi(w0.w) + bf_hi(w1.w)) + (bf_hi(w2.w) + bf_hi(w3.w));
    }
    for (; e + 8 <= e1; e += 8) {
        int sA = csr_src[e + sub];
        int sB = csr_src[e + 4 + sub];
        uint4 wA = H4[(size_t)sA * 16 + li];
        uint4 wB = H4[(size_t)sB * 16 + li];
        a0 += bf_lo(wA.x) + bf_lo(wB.x); a1 += bf_hi(wA.x) + bf_hi(wB.x);
        a2 += bf_lo(wA.y) + bf_lo(wB.y); a3 += bf_hi(wA.y) + bf_hi(wB.y);
        a4 += bf_lo(wA.z) + bf_lo(wB.z); a5 += bf_hi(wA.z) + bf_hi(wB.z);
        a6 += bf_lo(wA.w) + bf_lo(wB.w); a7 += bf_hi(wA.w) + bf_hi(wB.w);
    }
    for (; e < e1; e += 4) {
        int ee = e + sub;
        if (ee < e1) {
            int s = csr_src[ee];
            uint4 w = H4[(size_t)s * 16 + li];
            a0 += bf_lo(w.x); a1 += bf_hi(w.x);
            a2 += bf_lo(w.y); a3 += bf_hi(w.y);
            a4 += bf_lo(w.z); a5 += bf_hi(w.z);
            a6 += bf_lo(w.w); a7 += bf_hi(w.w);
        }
    }
#pragma unroll
    for (int d = 16; d <= 32; d <<= 1) {
        a0 += __shfl_xor(a0, d); a1 += __shfl_xor(a1, d);
        a2 += __shfl_xor(a2, d); a3 += __shfl_xor(a3, d);
        a4 += __shfl_xor(a4, d); a5 += __shfl_xor(a5, d);
        a6 += __shfl_xor(a6, d); a7 += __shfl_xor(a7, d);
    }
    if (sub == 0) {
        float di = dinv[node];
        const float4* b4 = (const float4*)bias;
        float4 bA = b4[li * 2], bB = b4[li * 2 + 1];
        float r0 = fmaxf(fmaf(di, a0, bA.x), 0.f);
        float r1 = fmaxf(fmaf(di, a1, bA.y), 0.f);
        float r2 = fmaxf(fmaf(di, a2, bA.z), 0.f);
        float r3 = fmaxf(fmaf(di, a3, bA.w), 0.f);
        float r4 = fmaxf(fmaf(di, a4, bB.x), 0.f);
        float r5 = fmaxf(fmaf(di, a5, bB.y), 0.f);
        float r6 = fmaxf(fmaf(di, a6, bB.z), 0.f);
        float r7 = fmaxf(fmaf(di, a7, bB.w), 0.f);
        uint4 o;
        o.x = pack2(r0, r1); o.y = pack2(r2, r3);
        o.z = pack2(r4, r5); o.w = pack2(r6, r7);
        out4[(size_t)node * 16 + li] = o;
    }
}

// ---------------------------------------------------------------- mean pool
__global__ __launch_bounds__(128) void k_pool(const unsigned short* __restrict__ A,
                                              const int* __restrict__ batch,
                                              float* __restrict__ emb) {
    int g = blockIdx.x;
    int c = threadIdx.x;
    int lo = 0, hi = NN;
    while (lo < hi) { int m = (lo + hi) >> 1; if (batch[m] < g) lo = m + 1; else hi = m; }
    int start = lo;
    hi = NN;
    while (lo < hi) { int m = (lo + hi) >> 1; if (batch[m] < g + 1) lo = m + 1; else hi = m; }
    int end = lo;
    float s = 0.f;
    for (int i = start; i < end; i++)
        s += __uint_as_float((unsigned int)A[(size_t)i * 128 + c] << 16);
    int cnt = end - start;
    emb[g * 128 + c] = s / (float)max(cnt, 1);
}

// ---------------------------------------------------------------- head MLP
__global__ __launch_bounds__(128) void k_head(const float* __restrict__ emb,
                                              const float* __restrict__ u,
                                              const float* __restrict__ Wh1,
                                              const float* __restrict__ bh1,
                                              const float* __restrict__ Wh2,
                                              const float* __restrict__ bh2,
                                              float* __restrict__ out) {
    __shared__ float hc[192];
    __shared__ float tt[128];
    int g = blockIdx.x, t = threadIdx.x;
    hc[t] = emb[g * 128 + t];
    if (t < 64) hc[128 + t] = u[g * 64 + t];
    __syncthreads();
    float acc = bh1[t];
    for (int k = 0; k < 192; k++) acc = fmaf(hc[k], Wh1[k * 128 + t], acc);
    tt[t] = fmaxf(acc, 0.f);
    __syncthreads();
    if (t < 2) {
        float o = bh2[t];
        for (int c2 = 0; c2 < 128; c2++) o = fmaf(tt[c2], Wh2[c2 * 2 + t], o);
        out[g * 2 + t] = o;
    }
}

// ---------------------------------------------------------------- launcher
extern "C" void kernel_launch(void* const* d_in, const int* in_sizes, int n_in,
                              void* d_out, int out_size, void* d_ws, size_t ws_size,
                              hipStream_t stream) {
    const float* x   = (const float*)d_in[0];
    const int*   ei  = (const int*)d_in[1];
    const int*   row = ei;        // edge_index[0] = src
    const int*   col = ei + NE;   // edge_index[1] = dst
    const float* u   = (const float*)d_in[2];
    const int*   batch = (const int*)d_in[3];
    const float* W1  = (const float*)d_in[5];
    const float* b1  = (const float*)d_in[6];
    const float* W2  = (const float*)d_in[7];
    const float* b2  = (const float*)d_in[8];
    const float* Wh1 = (const float*)d_in[9];
    const float* bh1 = (const float*)d_in[10];
    const float* Wh2 = (const float*)d_in[11];
    const float* bh2 = (const float*)d_in[12];
    float* out = (float*)d_out;

    char* ws = (char*)d_ws;
    size_t o = 0;
    auto alloc = [&](size_t bytes) -> void* {
        void* p = ws + o;
        o += (bytes + 511) & ~(size_t)511;
        return p;
    };
    unsigned short* Xbf = (unsigned short*)alloc((size_t)NN * 128 * 2);  // also A1 (aliased)
    unsigned short* Hsb = (unsigned short*)alloc((size_t)NN * 128 * 2);
    unsigned short* A2b = (unsigned short*)alloc((size_t)NN * 128 * 2);
    float* dinv   = (float*)alloc((size_t)NN * 4);
    int*   off    = (int*)alloc((size_t)NN * 4);
    int*   degw   = (int*)alloc((size_t)NN * 4);
    int*   csr_src= (int*)alloc((size_t)NBK * SLOT * 4);
    unsigned int* tmp = (unsigned int*)alloc((size_t)NBK * SLOT * 4);
    int*   gcur   = (int*)alloc((size_t)256 * 4);
    float* emb    = (float*)alloc((size_t)NG * 128 * 4);
    unsigned short* A1bf = Xbf;

    // --- CSR build via slack-region binning ---
    k_ginit<<<1, 256, 0, stream>>>(gcur);
    k_bin2<<<400, 256, 0, stream>>>(row, col, gcur, tmp);
    k_bucket<<<NBK, 256, 0, stream>>>(tmp, gcur, off, degw, dinv, csr_src);

    // --- cast input ---
    k_cast<<<NN * 128 / (256 * 8), 256, 0, stream>>>(x, (uint*)Xbf);

    // --- layer 1 ---
    k_gemm<<<cdiv(NN, 128), 256, 0, stream>>>(Xbf, W1, dinv, Hsb);
    k_agg<<<NN / 4, 256, 0, stream>>>((const uint4*)Hsb, off, degw, csr_src,
                                      dinv, b1, (uint4*)A1bf);
    // --- layer 2 ---
    k_gemm<<<cdiv(NN, 128), 256, 0, stream>>>(A1bf, W2, dinv, Hsb);
    k_agg<<<NN / 4, 256, 0, stream>>>((const uint4*)Hsb, off, degw, csr_src,
                                      dinv, b2, (uint4*)A2b);

    // --- mean pool + head ---
    k_pool<<<NG, 128, 0, stream>>>(A2b, batch, emb);
    k_head<<<NG, 128, 0, stream>>>(emb, u, Wh1, bh1, Wh2, bh2, out);
}